// Round 11
// baseline (564.854 us; speedup 1.0000x reference)
//
#include <hip/hip_runtime.h>
#include <hip/hip_bf16.h>

// ---------------------------------------------------------------------------
// MQ Parallel-FF Transformer block, MI355X (gfx950)
// Round 11: attention — raw s_barrier + counted waits (no per-tile vmcnt
//           drain; prefetch stays in flight through compute), and
//           __launch_bounds__(256,4) to force VGPR<=128 for 4 waves/SIMD.
//           Everything else unchanged from round 10.
// ---------------------------------------------------------------------------

typedef __attribute__((ext_vector_type(8))) short bf16x8;   // 8 bf16 (4 VGPR)
typedef __attribute__((ext_vector_type(4))) short s16x4;
typedef __attribute__((ext_vector_type(4))) float f32x4;

__device__ __forceinline__ short f2b(float f) {
  union { float f; unsigned u; } v; v.f = f;
  unsigned r = (v.u + 0x7fffu + ((v.u >> 16) & 1u)) >> 16;
  return (short)r;
}

__device__ __forceinline__ void gload16(const short* g, short* l) {
  __builtin_amdgcn_global_load_lds(
      (const __attribute__((address_space(1))) void*)g,
      (__attribute__((address_space(3))) void*)l, 16, 0, 0);
}

// ---------------- f32 [K][N] -> bf16 [N][K] transpose-convert ---------------
__global__ __launch_bounds__(256) void cvtT_kernel(const float* __restrict__ in,
                                                   short* __restrict__ out,
                                                   int K, int N) {
  __shared__ float tile[32][33];
  int n0 = blockIdx.x * 32, k0 = blockIdx.y * 32;
  int tx = threadIdx.x & 7, ty = threadIdx.x >> 3;     // 8 x 32
  float4 v = *(const float4*)&in[(size_t)(k0 + ty) * N + n0 + tx * 4];
  tile[ty][tx * 4 + 0] = v.x;
  tile[ty][tx * 4 + 1] = v.y;
  tile[ty][tx * 4 + 2] = v.z;
  tile[ty][tx * 4 + 3] = v.w;
  __syncthreads();
  s16x4 o = { f2b(tile[tx * 4 + 0][ty]), f2b(tile[tx * 4 + 1][ty]),
              f2b(tile[tx * 4 + 2][ty]), f2b(tile[tx * 4 + 3][ty]) };
  *(s16x4*)&out[(size_t)(n0 + ty) * K + k0 + tx * 4] = o;
}

// --------------------------------- LayerNorm -------------------------------
__global__ __launch_bounds__(256) void ln_kernel(const float* __restrict__ in,
                                                 const float* __restrict__ gamma,
                                                 short* __restrict__ out16,
                                                 float* __restrict__ out32) {
  int row = blockIdx.x;
  int t = threadIdx.x;
  float4 v = ((const float4*)(in + (size_t)row * 1024))[t];
  float s  = v.x + v.y + v.z + v.w;
  float sq = v.x*v.x + v.y*v.y + v.z*v.z + v.w*v.w;
  __shared__ float ssum[256], ssq[256];
  ssum[t] = s; ssq[t] = sq;
  __syncthreads();
  for (int o = 128; o > 0; o >>= 1) {
    if (t < o) { ssum[t] += ssum[t + o]; ssq[t] += ssq[t + o]; }
    __syncthreads();
  }
  float mu  = ssum[0] * (1.0f / 1024.0f);
  float var = ssq[0] * (1.0f / 1024.0f) - mu * mu;
  float rs  = rsqrtf(var + 1e-5f);
  float4 g = ((const float4*)gamma)[t];
  float o0 = (v.x - mu) * rs * g.x;
  float o1 = (v.y - mu) * rs * g.y;
  float o2 = (v.z - mu) * rs * g.z;
  float o3 = (v.w - mu) * rs * g.w;
  if (out16) {
    s16x4 o = { f2b(o0), f2b(o1), f2b(o2), f2b(o3) };
    ((s16x4*)out16)[(size_t)row * 256 + t] = o;
  }
  if (out32) {
    float4 o = { o0, o1, o2, o3 };
    ((float4*)out32)[(size_t)row * 256 + t] = o;
  }
}

// ------------------------------- GEMM (ring) -------------------------------
// C[M,N] = A[M,K] @ B^T, B stored [N][Kstride] bf16. BMxBN tile, BK=32,
// 256 thr (4 waves 2x2), ring DEPTH=4, counted vmcnt, 1 barrier/K-tile.
template<int EPI, int BM, int BN>
__global__ __launch_bounds__(256, 2) void gemm_ring(
    const short* __restrict__ A, const short* __restrict__ B,
    int M, int N, int Kstride, int Klen,
    short* __restrict__ out16, float* __restrict__ out32,
    const float* __restrict__ res, float scale)
{
  constexpr int DEPTH = 4;
  constexpr int FM = BM / 32;
  constexpr int FN = BN / 32;
  constexpr int AL = BM / 64;
  constexpr int BL = BN / 64;
  __shared__ __align__(16) short As[DEPTH][BM * 32];
  __shared__ __align__(16) short Bs[DEPTH][BN * 32];

  int t = threadIdx.x;
  int lane = t & 63, wave = t >> 6;
  int wm = wave >> 1, wn = wave & 1;
  int lrow = lane & 15, lgrp = lane >> 4;
  int m0 = blockIdx.y * BM, n0 = blockIdx.x * BN;
  int kbase = blockIdx.z * Klen;

  int srow = lane >> 2, scol = (lane & 3) * 8;
  const short* gA = A + (size_t)(m0 + wave * 16 + srow) * Kstride + kbase + scol;
  const short* gB = B + (size_t)(n0 + wave * 16 + srow) * Kstride + kbase + scol;

  auto STAGE = [&](int slot, int kt) {
    int k0 = kt * 32;
#pragma unroll
    for (int i = 0; i < AL; i++)
      gload16(gA + (size_t)(i * 64) * Kstride + k0, &As[slot][(i * 4 + wave) * 512]);
#pragma unroll
    for (int j = 0; j < BL; j++)
      gload16(gB + (size_t)(j * 64) * Kstride + k0, &Bs[slot][(j * 4 + wave) * 512]);
  };

  f32x4 acc[FM][FN];
  const f32x4 zero = { 0.f, 0.f, 0.f, 0.f };
#pragma unroll
  for (int i = 0; i < FM; i++)
#pragma unroll
    for (int j = 0; j < FN; j++) acc[i][j] = zero;

  int nt = Klen / 32;
#pragma unroll
  for (int p = 0; p < DEPTH - 1; p++) STAGE(p, p);

  int slot = 0, stage_slot = DEPTH - 1;
  for (int tI = 0; tI < nt; ++tI) {
    int rem = nt - 1 - tI;
    if constexpr (AL + BL == 4) {
      if (rem >= 2)      asm volatile("s_waitcnt vmcnt(8)" ::: "memory");
      else if (rem == 1) asm volatile("s_waitcnt vmcnt(4)" ::: "memory");
      else               asm volatile("s_waitcnt vmcnt(0)" ::: "memory");
    } else {             // AL+BL==3 (64x128)
      if (rem >= 2)      asm volatile("s_waitcnt vmcnt(6)" ::: "memory");
      else if (rem == 1) asm volatile("s_waitcnt vmcnt(3)" ::: "memory");
      else               asm volatile("s_waitcnt vmcnt(0)" ::: "memory");
    }
    __builtin_amdgcn_s_barrier();
    __builtin_amdgcn_sched_barrier(0);

    if (tI + DEPTH - 1 < nt) STAGE(stage_slot, tI + DEPTH - 1);

    bf16x8 af[FM], bfr[FN];
#pragma unroll
    for (int mf = 0; mf < FM; mf++)
      af[mf] = *(const bf16x8*)&As[slot][(wm * (BM / 2) + mf * 16 + lrow) * 32 + lgrp * 8];
#pragma unroll
    for (int nf = 0; nf < FN; nf++)
      bfr[nf] = *(const bf16x8*)&Bs[slot][(wn * (BN / 2) + nf * 16 + lrow) * 32 + lgrp * 8];

    __builtin_amdgcn_s_setprio(1);
#pragma unroll
    for (int mf = 0; mf < FM; mf++)
#pragma unroll
      for (int nf = 0; nf < FN; nf++)
        acc[mf][nf] = __builtin_amdgcn_mfma_f32_16x16x32_bf16(af[mf], bfr[nf], acc[mf][nf], 0, 0, 0);
    __builtin_amdgcn_s_setprio(0);

    slot = (slot + 1 == DEPTH) ? 0 : slot + 1;
    stage_slot = (stage_slot + 1 == DEPTH) ? 0 : stage_slot + 1;
  }

#pragma unroll
  for (int mf = 0; mf < FM; mf++)
#pragma unroll
    for (int nf = 0; nf < FN; nf++)
#pragma unroll
      for (int r = 0; r < 4; r++) {
        int row = m0 + wm * (BM / 2) + mf * 16 + lgrp * 4 + r;
        int col = n0 + wn * (BN / 2) + nf * 16 + lrow;
        float v = acc[mf][nf][r];
        if (EPI == 0) {
          out16[(size_t)row * N + col] = f2b(v * scale);
        } else if (EPI == 1) {
          out32[(size_t)row * N + col] = v + res[(size_t)row * N + col];
        } else {   // EPI 3: split-K partial
          out32[(size_t)blockIdx.z * M * N + (size_t)row * N + col] = v;
        }
      }
}

// --------------- Wff1 fused SwiGLU, m201-style 8-phase (dual) ---------------
// act[4096,4096] = silu(yn@Wg)*(yn@Wv); Wff1T stored [8192][1024] (val rows
// 0..4095, gate 4096..8191). BM=256, BN=128 (val)+128 (gate), BK=64,
// 512 thr (8 waves 2Mx4N), double-buffered 128KB LDS, 128B rows with 3-bit
// XOR swizzle: LDS[row][c16] = global[row][c16 ^ (row&7)] via pre-swizzled
// gload source; ds_read uses chunk = (kh*4+lgrp) ^ (row&7)  -> conflict-free.
// 4 phases/K-step: {ds_reads | prefetch gloads | bar | lgkm0 | 16 MFMA | bar}.
__global__ __launch_bounds__(512, 2) void gemm_ff1(
    const short* __restrict__ A, const short* __restrict__ B,
    short* __restrict__ out16)
{
  constexpr int K = 1024, NT = 16;   // 16 K-steps of 64
  __shared__ __align__(16) short As[2][256 * 64];   // 64 KB
  __shared__ __align__(16) short Bv[2][128 * 64];   // 32 KB
  __shared__ __align__(16) short Bg[2][128 * 64];   // 32 KB

  int t = threadIdx.x;
  int lane = t & 63, wave = t >> 6;
  int wm = wave >> 2, wn = wave & 3;          // 2M x 4N
  int lrow = lane & 15, lgrp = lane >> 4;
  int m0 = blockIdx.y * 256, n0 = blockIdx.x * 128;

  // staging: one gload line/wave = 8 rows x 128B. lane l -> row +(l>>3),
  // 16B chunk l&7 (linear LDS). Source chunk pre-swizzled: (l&7)^(l>>3).
  int srow8 = lane >> 3;
  int schunk = ((lane & 7) ^ srow8) * 8;
  const short* gA  = A + (size_t)(m0 + wave * 8 + srow8) * K + schunk;
  const short* gBv = B + (size_t)(n0 + wave * 8 + srow8) * K + schunk;
  const short* gBg = B + (size_t)(4096 + n0 + wave * 8 + srow8) * K + schunk;

  f32x4 acc[8][2], acc2[8][2];
  const f32x4 zero = { 0.f, 0.f, 0.f, 0.f };
#pragma unroll
  for (int i = 0; i < 8; i++) {
    acc[i][0] = zero; acc[i][1] = zero; acc2[i][0] = zero; acc2[i][1] = zero;
  }

  // swizzled ds_read chunk offsets (shorts): ((kh*4+lgrp) ^ (lrow&7)) * 8
  int rc0 = ((lgrp) ^ (lrow & 7)) * 8;          // kh = 0
  int rc1 = ((4 | lgrp) ^ (lrow & 7)) * 8;      // kh = 1

  // prologue: stage tile 0 fully (8 lines)
#pragma unroll
  for (int i = 0; i < 4; i++)
    gload16(gA + (size_t)(i * 64) * K, &As[0][(i * 64 + wave * 8) * 64]);
#pragma unroll
  for (int j = 0; j < 2; j++) {
    gload16(gBv + (size_t)(j * 64) * K, &Bv[0][(j * 64 + wave * 8) * 64]);
    gload16(gBg + (size_t)(j * 64) * K, &Bg[0][(j * 64 + wave * 8) * 64]);
  }
  asm volatile("s_waitcnt vmcnt(0)" ::: "memory");
  __builtin_amdgcn_s_barrier();
  __builtin_amdgcn_sched_barrier(0);

  for (int tI = 0; tI < NT; ++tI) {
    int cur = tI & 1, nxt = cur ^ 1;
    bool pf = (tI + 1 < NT);
    int kn = (tI + 1) * 64;
    bf16x8 af0[8], af1[8], bvf[2], bgf[2];

    // ---------------- phase 0: val, k-half 0 -------------------------------
#pragma unroll
    for (int mf = 0; mf < 8; mf++)
      af0[mf] = *(const bf16x8*)&As[cur][(wm * 128 + mf * 16 + lrow) * 64 + rc0];
    bvf[0] = *(const bf16x8*)&Bv[cur][(wn * 32 + lrow) * 64 + rc0];
    bvf[1] = *(const bf16x8*)&Bv[cur][(wn * 32 + 16 + lrow) * 64 + rc0];
    if (pf) {
      gload16(gA + kn,                     &As[nxt][(wave * 8) * 64]);
      gload16(gA + (size_t)64 * K + kn,    &As[nxt][(64 + wave * 8) * 64]);
      gload16(gA + (size_t)128 * K + kn,   &As[nxt][(128 + wave * 8) * 64]);
    }
    __builtin_amdgcn_s_barrier();
    asm volatile("s_waitcnt lgkmcnt(0)" ::: "memory");
    __builtin_amdgcn_sched_barrier(0);
    __builtin_amdgcn_s_setprio(1);
#pragma unroll
    for (int mf = 0; mf < 8; mf++) {
      acc[mf][0] = __builtin_amdgcn_mfma_f32_16x16x32_bf16(af0[mf], bvf[0], acc[mf][0], 0, 0, 0);
      acc[mf][1] = __builtin_amdgcn_mfma_f32_16x16x32_bf16(af0[mf], bvf[1], acc[mf][1], 0, 0, 0);
    }
    __builtin_amdgcn_s_setprio(0);
    __builtin_amdgcn_s_barrier();
    __builtin_amdgcn_sched_barrier(0);

    // ---------------- phase 1: val, k-half 1 -------------------------------
#pragma unroll
    for (int mf = 0; mf < 8; mf++)
      af1[mf] = *(const bf16x8*)&As[cur][(wm * 128 + mf * 16 + lrow) * 64 + rc1];
    bvf[0] = *(const bf16x8*)&Bv[cur][(wn * 32 + lrow) * 64 + rc1];
    bvf[1] = *(const bf16x8*)&Bv[cur][(wn * 32 + 16 + lrow) * 64 + rc1];
    if (pf) {
      gload16(gA + (size_t)192 * K + kn,   &As[nxt][(192 + wave * 8) * 64]);
      gload16(gBv + kn,                    &Bv[nxt][(wave * 8) * 64]);
      gload16(gBv + (size_t)64 * K + kn,   &Bv[nxt][(64 + wave * 8) * 64]);
    }
    __builtin_amdgcn_s_barrier();
    asm volatile("s_waitcnt lgkmcnt(0)" ::: "memory");
    __builtin_amdgcn_sched_barrier(0);
    __builtin_amdgcn_s_setprio(1);
#pragma unroll
    for (int mf = 0; mf < 8; mf++) {
      acc[mf][0] = __builtin_amdgcn_mfma_f32_16x16x32_bf16(af1[mf], bvf[0], acc[mf][0], 0, 0, 0);
      acc[mf][1] = __builtin_amdgcn_mfma_f32_16x16x32_bf16(af1[mf], bvf[1], acc[mf][1], 0, 0, 0);
    }
    __builtin_amdgcn_s_setprio(0);
    __builtin_amdgcn_s_barrier();
    __builtin_amdgcn_sched_barrier(0);

    // ---------------- phase 2: gate, k-half 0 ------------------------------
    bgf[0] = *(const bf16x8*)&Bg[cur][(wn * 32 + lrow) * 64 + rc0];
    bgf[1] = *(const bf16x8*)&Bg[cur][(wn * 32 + 16 + lrow) * 64 + rc0];
    if (pf) {
      gload16(gBg + kn,                    &Bg[nxt][(wave * 8) * 64]);
      gload16(gBg + (size_t)64 * K + kn,   &Bg[nxt][(64 + wave * 8) * 64]);
    }
    __builtin_amdgcn_s_barrier();
    asm volatile("s_waitcnt lgkmcnt(0)" ::: "memory");
    __builtin_amdgcn_sched_barrier(0);
    __builtin_amdgcn_s_setprio(1);
#pragma unroll
    for (int mf = 0; mf < 8; mf++) {
      acc2[mf][0] = __builtin_amdgcn_mfma_f32_16x16x32_bf16(af0[mf], bgf[0], acc2[mf][0], 0, 0, 0);
      acc2[mf][1] = __builtin_amdgcn_mfma_f32_16x16x32_bf16(af0[mf], bgf[1], acc2[mf][1], 0, 0, 0);
    }
    __builtin_amdgcn_s_setprio(0);
    __builtin_amdgcn_s_barrier();
    __builtin_amdgcn_sched_barrier(0);

    // ---------------- phase 3: gate, k-half 1 (no prefetch) ----------------
    bgf[0] = *(const bf16x8*)&Bg[cur][(wn * 32 + lrow) * 64 + rc1];
    bgf[1] = *(const bf16x8*)&Bg[cur][(wn * 32 + 16 + lrow) * 64 + rc1];
    __builtin_amdgcn_s_barrier();
    asm volatile("s_waitcnt lgkmcnt(0)" ::: "memory");
    __builtin_amdgcn_sched_barrier(0);
    __builtin_amdgcn_s_setprio(1);
#pragma unroll
    for (int mf = 0; mf < 8; mf++) {
      acc2[mf][0] = __builtin_amdgcn_mfma_f32_16x16x32_bf16(af1[mf], bgf[0], acc2[mf][0], 0, 0, 0);
      acc2[mf][1] = __builtin_amdgcn_mfma_f32_16x16x32_bf16(af1[mf], bgf[1], acc2[mf][1], 0, 0, 0);
    }
    __builtin_amdgcn_s_setprio(0);
    __builtin_amdgcn_s_barrier();
    __builtin_amdgcn_sched_barrier(0);

    // end of step: tile t+1's loads (issued phases 0-2, >=1.5 phases ago)
    asm volatile("s_waitcnt vmcnt(0)" ::: "memory");
    __builtin_amdgcn_s_barrier();
    __builtin_amdgcn_sched_barrier(0);
  }

  // epilogue: act = silu(gate) * val
#pragma unroll
  for (int mf = 0; mf < 8; mf++)
#pragma unroll
    for (int nf = 0; nf < 2; nf++)
#pragma unroll
      for (int r = 0; r < 4; r++) {
        int row = m0 + wm * 128 + mf * 16 + lgrp * 4 + r;
        int col = n0 + wn * 32 + nf * 16 + lrow;
        float v = acc[mf][nf][r];
        float gate = acc2[mf][nf][r];
        float sig = 1.0f / (1.0f + __expf(-gate));
        out16[(size_t)row * 4096 + col] = f2b(v * gate * sig);
      }
}

// ---------------- split-K reduce: kv16 = bf16(sum_z partial[z]) ------------
__global__ __launch_bounds__(256) void kvred_kernel(const float* __restrict__ p,
                                                    short* __restrict__ out, int n4) {
  int i = blockIdx.x * 256 + threadIdx.x;
  if (i >= n4) return;
  const int S = 4096 * 128 / 4;
  float4 a = ((const float4*)p)[i];
  float4 b = ((const float4*)p)[i + S];
  float4 c = ((const float4*)p)[i + 2 * S];
  float4 d = ((const float4*)p)[i + 3 * S];
  s16x4 o = { f2b(a.x + b.x + c.x + d.x), f2b(a.y + b.y + c.y + d.y),
              f2b(a.z + b.z + c.z + d.z), f2b(a.w + b.w + c.w + d.w) };
  ((s16x4*)out)[i] = o;
}

// ------------------------------- Attention ---------------------------------
// MQA flash attention. QBLK=32/wave; 4 waves/block share swizzled K/V tiles.
// Raw-barrier pipeline: per KV tile, loads for tile j+1 are issued right
// after the LDS write of tile j and stay in flight through the whole
// compute phase (no vmcnt drain at any barrier).
__global__ __launch_bounds__(256, 4) void attn_kernel(const short* __restrict__ q,
                                                      const short* __restrict__ kv,
                                                      short* __restrict__ ao)
{
  __shared__ __align__(16) short Ks[64 * 64];      // [kv][d]   swizzled
  __shared__ __align__(16) short Vs[64 * 64];      // [d][kv]   swizzled
  __shared__ __align__(16) short Ps[4][32 * 64];   // per-wave [q][kv] swizzled

  int t = threadIdx.x;
  int lane = t & 63, wave = t >> 6;
  int lrow = lane & 15, lgrp = lane >> 4;
  int qt = blockIdx.x;
  int b = blockIdx.y >> 2, hg = blockIdx.y & 3;
  int h = hg * 4 + wave;

  char* Kb = (char*)Ks;
  char* Vb = (char*)Vs;
  char* Pb = (char*)Ps + wave * (32 * 64 * 2);

  bf16x8 qf[2][2];
  const short* qb = q + ((size_t)(b * 1024 + qt * 32)) * 1024 + h * 64;
#pragma unroll
  for (int mf = 0; mf < 2; mf++)
#pragma unroll
    for (int kk = 0; kk < 2; kk++)
      qf[mf][kk] = *(const bf16x8*)&qb[(size_t)(mf * 16 + lrow) * 1024 + kk * 32 + lgrp * 8];

  f32x4 oacc[2][4];
  float m_[2][4], l_[2][4];
  const f32x4 zero = { 0.f, 0.f, 0.f, 0.f };
#pragma unroll
  for (int i = 0; i < 2; i++)
#pragma unroll
    for (int j = 0; j < 4; j++) { oacc[i][j] = zero; }
#pragma unroll
  for (int i = 0; i < 2; i++)
#pragma unroll
    for (int r = 0; r < 4; r++) { m_[i][r] = -3.0e38f; l_[i][r] = 0.f; }

  // prologue: issue KV tile 0 loads (land at first loop-top vmcnt)
  int4 d[4];
  {
    const short* kvb = kv + ((size_t)(b * 1024 + lane)) * 128 + wave * 32;
#pragma unroll
    for (int i = 0; i < 4; i++) d[i] = ((const int4*)kvb)[i];
  }

  for (int j0 = 0; j0 < 1024; j0 += 64) {
    __builtin_amdgcn_s_barrier();        // all waves done reading prev K/V
    __builtin_amdgcn_sched_barrier(0);
    asm volatile("s_waitcnt vmcnt(0)" ::: "memory");   // d[] arrived
    if (wave < 2) {
      int sw = (lane & 7) << 4;
#pragma unroll
      for (int i = 0; i < 4; i++)
        *(int4*)(Kb + lane * 128 + ((wave * 64 + i * 16) ^ sw)) = d[i];
    } else {
#pragma unroll
      for (int i = 0; i < 4; i++) {
        union { int4 v; short s[8]; } u; u.v = d[i];
#pragma unroll
        for (int j = 0; j < 8; j++) {
          int dd = (wave - 2) * 32 + i * 8 + j;
          *(short*)(Vb + dd * 128 + ((lane * 2) ^ ((dd & 7) << 4))) = u.s[j];
        }
      }
    }
    // issue next tile's loads; they stay in flight through compute
    if (j0 + 64 < 1024) {
      const short* kvn = kv + ((size_t)(b * 1024 + j0 + 64 + lane)) * 128 + wave * 32;
#pragma unroll
      for (int i = 0; i < 4; i++) d[i] = ((const int4*)kvn)[i];
    }
    asm volatile("s_waitcnt lgkmcnt(0)" ::: "memory");  // LDS writes visible
    __builtin_amdgcn_s_barrier();
    __builtin_amdgcn_sched_barrier(0);

    // ---- S = Q @ K^T ----
    bf16x8 kf[4][2];
#pragma unroll
    for (int nf = 0; nf < 4; nf++) {
      int row = nf * 16 + lrow, sw = (row & 7) << 4;
      kf[nf][0] = *(const bf16x8*)(Kb + row * 128 + ((lgrp * 16) ^ sw));
      kf[nf][1] = *(const bf16x8*)(Kb + row * 128 + ((64 + lgrp * 16) ^ sw));
    }
    f32x4 sacc[2][4];
#pragma unroll
    for (int i = 0; i < 2; i++)
#pragma unroll
      for (int j = 0; j < 4; j++) sacc[i][j] = zero;
    __builtin_amdgcn_s_setprio(1);
#pragma unroll
    for (int mf = 0; mf < 2; mf++)
#pragma unroll
      for (int nf = 0; nf < 4; nf++)
#pragma unroll
        for (int kk = 0; kk < 2; kk++)
          sacc[mf][nf] = __builtin_amdgcn_mfma_f32_16x16x32_bf16(qf[mf][kk], kf[nf][kk], sacc[mf][nf], 0, 0, 0);
    __builtin_amdgcn_s_setprio(0);

    // ---- online softmax with defer-max (T13) ----
    float pmax[2][4];
    bool okd = true;
#pragma unroll
    for (int mf = 0; mf < 2; mf++)
#pragma unroll
      for (int r = 0; r < 4; r++) {
        float pm = fmaxf(fmaxf(sacc[mf][0][r], sacc[mf][1][r]),
                         fmaxf(sacc[mf][2][r], sacc[mf][3][r]));
        pmax[mf][r] = pm;
        okd = okd && (pm <= m_[mf][r] + 8.0f);
      }
    if (__all(okd)) {
#pragma unroll
      for (int mf = 0; mf < 2; mf++)
#pragma unroll
        for (int r = 0; r < 4; r++) {
          int row = mf * 16 + lgrp * 4 + r, sw = (row & 7) << 4;
          float al = 0.f;
#pragma unroll
          for (int nf = 0; nf < 4; nf++) {
            float p = __expf(sacc[mf][nf][r] - m_[mf][r]);
            *(short*)(Pb + row * 128 + (((nf * 16 + lrow) * 2) ^ sw)) = f2b(p);
            al += p;
          }
          l_[mf][r] += al;
        }
    } else {
#pragma unroll
      for (int mf = 0; mf < 2; mf++)
#pragma unroll
        for (int r = 0; r < 4; r++) {
          float mx = pmax[mf][r];
#pragma unroll
          for (int o = 8; o >= 1; o >>= 1) mx = fmaxf(mx, __shfl_xor(mx, o));
          float mnew = fmaxf(m_[mf][r], mx);
          float corr = __expf(m_[mf][r] - mnew);
          int row = mf * 16 + lgrp * 4 + r, sw = (row & 7) << 4;
          float al = 0.f;
#pragma unroll
          for (int nf = 0; nf < 4; nf++) {
            float p = __expf(sacc[mf][nf][r] - mnew);
            *(short*)(Pb + row * 128 + (((nf * 16 + lrow) * 2) ^ sw)) = f2b(p);
            al += p;
          }
          l_[mf][r] = l_[mf][r] * corr + al;
          m_[mf][r] = mnew;
#pragma unroll
          for (int nf = 0; nf < 4; nf++) oacc[mf][nf][r] *= corr;
        }
    }

    // ---- O += P @ V ----  (P is wave-private: no barrier needed)
    bf16x8 vf[4][2], pfr[2][2];
#pragma unroll
    for (int nf = 0; nf < 4; nf++) {
      int row = nf * 16 + lrow, sw = (row & 7) << 4;
      vf[nf][0] = *(const bf16x8*)(Vb + row * 128 + ((lgrp * 16) ^ sw));
      vf[nf][1] = *(const bf16x8*)(Vb + row * 128 + ((64 + lgrp * 16) ^ sw));
    }
#pragma unroll
    for (int mf = 0; mf < 2; mf++) {
      int row = mf * 16 + lrow, sw = (row & 7) << 4;
      pfr[mf][0] = *(const bf16x8*)(Pb + row * 128 + ((lgrp * 16) ^ sw));
      pfr[mf][1] = *(const bf16x8*)(Pb + row * 128 + ((64 + lgrp * 16) ^ sw));
    }
    __builtin_amdgcn_s_setprio(1);
#pragma unroll
    for (int mf = 0; mf < 2; mf++)
#pragma unroll
      for (int nf = 0; nf < 4; nf++)
#pragma unroll
        for (int kk = 0; kk < 2; kk++)
          oacc[mf][nf] = __builtin_amdgcn_mfma_f32_16x16x32_bf16(pfr[mf][kk], vf[nf][kk], oacc[mf][nf], 0, 0, 0);
    __builtin_amdgcn_s_setprio(0);
  }

  // final l reduction + write
#pragma unroll
  for (int mf = 0; mf < 2; mf++)
#pragma unroll
    for (int r = 0; r < 4; r++) {
      float ls = l_[mf][r];
#pragma unroll
      for (int o = 8; o >= 1; o >>= 1) ls += __shfl_xor(ls, o);
      float inv = 1.0f / ls;
      int qrow = qt * 32 + mf * 16 + lgrp * 4 + r;
#pragma unroll
      for (int nf = 0; nf < 4; nf++) {
        float val = oacc[mf][nf][r] * inv;
        ao[((size_t)(b * 1024 + qrow)) * 1024 + h * 64 + nf * 16 + lrow] = f2b(val);
      }
    }
}

// ------------------------------- launcher ----------------------------------
extern "C" void kernel_launch(void* const* d_in, const int* in_sizes, int n_in,
                              void* d_out, int out_size, void* d_ws, size_t ws_size,
                              hipStream_t stream) {
  const float* x     = (const float*)d_in[0];
  const float* y     = (const float*)d_in[1];
  const float* g1    = (const float*)d_in[2];
  const float* g2    = (const float*)d_in[3];
  const float* g_out = (const float*)d_in[4];
  const float* Wq    = (const float*)d_in[5];
  const float* Wkv   = (const float*)d_in[6];
  const float* Wo    = (const float*)d_in[7];
  const float* Wff1  = (const float*)d_in[8];
  const float* Wff2  = (const float*)d_in[9];

  char* ws = (char*)d_ws;
  size_t off = 0;
  auto alloc = [&](size_t bytes) { char* p = ws + off; off += bytes; return p; };
  short* wqT    = (short*)alloc((size_t)1024 * 1024 * 2);   // [1024][1024]
  short* wkvT   = (short*)alloc((size_t)128 * 1024 * 2);    // [128][1024]
  short* woT    = (short*)alloc((size_t)1024 * 1024 * 2);   // [1024][1024]
  short* wff1T  = (short*)alloc((size_t)8192 * 1024 * 2);   // [8192][1024]
  short* wff2T  = (short*)alloc((size_t)1024 * 4096 * 2);   // [1024][4096]
  short* xn16   = (short*)alloc((size_t)4096 * 1024 * 2);
  short* yn16   = (short*)alloc((size_t)4096 * 1024 * 2);
  float* ynf    = (float*)alloc((size_t)4096 * 1024 * 4);
  short* q16    = (short*)alloc((size_t)4096 * 1024 * 2);
  short* kv16   = (short*)alloc((size_t)4096 * 128 * 2);
  short* ao16   = (short*)alloc((size_t)4096 * 1024 * 2);
  float* lnout  = (float*)alloc((size_t)4096 * 1024 * 4);
  short* act16  = (short*)alloc((size_t)4096 * 4096 * 2);
  float* kvpart = (float*)alloc((size_t)4 * 4096 * 128 * 4);
  float* outf   = (float*)d_out;

  // weight transpose-convert: [K][N] f32 -> [N][K] bf16
  cvtT_kernel<<<dim3(1024 / 32, 1024 / 32), 256, 0, stream>>>(Wq,   wqT,   1024, 1024);
  cvtT_kernel<<<dim3(128 / 32, 1024 / 32),  256, 0, stream>>>(Wkv,  wkvT,  1024, 128);
  cvtT_kernel<<<dim3(1024 / 32, 1024 / 32), 256, 0, stream>>>(Wo,   woT,   1024, 1024);
  cvtT_kernel<<<dim3(8192 / 32, 1024 / 32), 256, 0, stream>>>(Wff1, wff1T, 1024, 8192);
  cvtT_kernel<<<dim3(1024 / 32, 4096 / 32), 256, 0, stream>>>(Wff2, wff2T, 4096, 1024);

  // LayerNorms
  ln_kernel<<<4096, 256, 0, stream>>>(x, g1, xn16, nullptr);
  ln_kernel<<<4096, 256, 0, stream>>>(y, g2, yn16, ynf);

  // q = (xn @ Wq) * 1/8   [BM=64: 512 blocks]
  gemm_ring<0, 64, 128><<<dim3(8, 64), 256, 0, stream>>>(
      xn16, wqT, 4096, 1024, 1024, 1024, q16, nullptr, nullptr, 0.125f);
  // kv = yn @ Wkv   [split-K x4; f32 partials]
  gemm_ring<3, 64, 128><<<dim3(1, 64, 4), 256, 0, stream>>>(
      yn16, wkvT, 4096, 128, 1024, 256, nullptr, kvpart, nullptr, 1.0f);
  kvred_kernel<<<512, 256, 0, stream>>>(kvpart, kv16, 4096 * 128 / 4);

  // attention
  attn_kernel<<<dim3(32, 16), 256, 0, stream>>>(q16, kv16, ao16);

  // out = attn @ Wo + yn   (f32, into d_out as scratch)
  gemm_ring<1, 64, 128><<<dim3(8, 64), 256, 0, stream>>>(
      ao16, woT, 4096, 1024, 1024, 1024, nullptr, outf, ynf, 1.0f);

  // ln_out = LN(out) * g_out  (f32)
  ln_kernel<<<4096, 256, 0, stream>>>(outf, g_out, nullptr, lnout);

  // act = silu(gate) * val   (m201-style 8-phase fused SwiGLU GEMM)
  gemm_ff1<<<dim3(32, 16), 512, 0, stream>>>(yn16, wff1T, act16);

  // d_out = act @ Wff2 + ln_out
  gemm_ring<1, 64, 128><<<dim3(8, 64), 256, 0, stream>>>(
      act16, wff2T, 4096, 1024, 4096, 4096, nullptr, outf, lnout, 1.0f);
}

// Round 12
// 316.694 us; speedup vs baseline: 1.7836x; 1.7836x over previous
//
#include <hip/hip_runtime.h>
#include <hip/hip_bf16.h>

// ---------------------------------------------------------------------------
// MQ Parallel-FF Transformer block, MI355X (gfx950)
// Round 12: revert the (256,4) launch bound (it forced VGPR=64 -> massive
//           scratch spills, FETCH 8MB->385MB). Keep raw-barrier counted-wait
//           attention pipeline. Everything else unchanged from round 11.
// ---------------------------------------------------------------------------

typedef __attribute__((ext_vector_type(8))) short bf16x8;   // 8 bf16 (4 VGPR)
typedef __attribute__((ext_vector_type(4))) short s16x4;
typedef __attribute__((ext_vector_type(4))) float f32x4;

__device__ __forceinline__ short f2b(float f) {
  union { float f; unsigned u; } v; v.f = f;
  unsigned r = (v.u + 0x7fffu + ((v.u >> 16) & 1u)) >> 16;
  return (short)r;
}

__device__ __forceinline__ void gload16(const short* g, short* l) {
  __builtin_amdgcn_global_load_lds(
      (const __attribute__((address_space(1))) void*)g,
      (__attribute__((address_space(3))) void*)l, 16, 0, 0);
}

// ---------------- f32 [K][N] -> bf16 [N][K] transpose-convert ---------------
__global__ __launch_bounds__(256) void cvtT_kernel(const float* __restrict__ in,
                                                   short* __restrict__ out,
                                                   int K, int N) {
  __shared__ float tile[32][33];
  int n0 = blockIdx.x * 32, k0 = blockIdx.y * 32;
  int tx = threadIdx.x & 7, ty = threadIdx.x >> 3;     // 8 x 32
  float4 v = *(const float4*)&in[(size_t)(k0 + ty) * N + n0 + tx * 4];
  tile[ty][tx * 4 + 0] = v.x;
  tile[ty][tx * 4 + 1] = v.y;
  tile[ty][tx * 4 + 2] = v.z;
  tile[ty][tx * 4 + 3] = v.w;
  __syncthreads();
  s16x4 o = { f2b(tile[tx * 4 + 0][ty]), f2b(tile[tx * 4 + 1][ty]),
              f2b(tile[tx * 4 + 2][ty]), f2b(tile[tx * 4 + 3][ty]) };
  *(s16x4*)&out[(size_t)(n0 + ty) * K + k0 + tx * 4] = o;
}

// --------------------------------- LayerNorm -------------------------------
__global__ __launch_bounds__(256) void ln_kernel(const float* __restrict__ in,
                                                 const float* __restrict__ gamma,
                                                 short* __restrict__ out16,
                                                 float* __restrict__ out32) {
  int row = blockIdx.x;
  int t = threadIdx.x;
  float4 v = ((const float4*)(in + (size_t)row * 1024))[t];
  float s  = v.x + v.y + v.z + v.w;
  float sq = v.x*v.x + v.y*v.y + v.z*v.z + v.w*v.w;
  __shared__ float ssum[256], ssq[256];
  ssum[t] = s; ssq[t] = sq;
  __syncthreads();
  for (int o = 128; o > 0; o >>= 1) {
    if (t < o) { ssum[t] += ssum[t + o]; ssq[t] += ssq[t + o]; }
    __syncthreads();
  }
  float mu  = ssum[0] * (1.0f / 1024.0f);
  float var = ssq[0] * (1.0f / 1024.0f) - mu * mu;
  float rs  = rsqrtf(var + 1e-5f);
  float4 g = ((const float4*)gamma)[t];
  float o0 = (v.x - mu) * rs * g.x;
  float o1 = (v.y - mu) * rs * g.y;
  float o2 = (v.z - mu) * rs * g.z;
  float o3 = (v.w - mu) * rs * g.w;
  if (out16) {
    s16x4 o = { f2b(o0), f2b(o1), f2b(o2), f2b(o3) };
    ((s16x4*)out16)[(size_t)row * 256 + t] = o;
  }
  if (out32) {
    float4 o = { o0, o1, o2, o3 };
    ((float4*)out32)[(size_t)row * 256 + t] = o;
  }
}

// ------------------------------- GEMM (ring) -------------------------------
// C[M,N] = A[M,K] @ B^T, B stored [N][Kstride] bf16. BMxBN tile, BK=32,
// 256 thr (4 waves 2x2), ring DEPTH=4, counted vmcnt, 1 barrier/K-tile.
template<int EPI, int BM, int BN>
__global__ __launch_bounds__(256, 2) void gemm_ring(
    const short* __restrict__ A, const short* __restrict__ B,
    int M, int N, int Kstride, int Klen,
    short* __restrict__ out16, float* __restrict__ out32,
    const float* __restrict__ res, float scale)
{
  constexpr int DEPTH = 4;
  constexpr int FM = BM / 32;
  constexpr int FN = BN / 32;
  constexpr int AL = BM / 64;
  constexpr int BL = BN / 64;
  __shared__ __align__(16) short As[DEPTH][BM * 32];
  __shared__ __align__(16) short Bs[DEPTH][BN * 32];

  int t = threadIdx.x;
  int lane = t & 63, wave = t >> 6;
  int wm = wave >> 1, wn = wave & 1;
  int lrow = lane & 15, lgrp = lane >> 4;
  int m0 = blockIdx.y * BM, n0 = blockIdx.x * BN;
  int kbase = blockIdx.z * Klen;

  int srow = lane >> 2, scol = (lane & 3) * 8;
  const short* gA = A + (size_t)(m0 + wave * 16 + srow) * Kstride + kbase + scol;
  const short* gB = B + (size_t)(n0 + wave * 16 + srow) * Kstride + kbase + scol;

  auto STAGE = [&](int slot, int kt) {
    int k0 = kt * 32;
#pragma unroll
    for (int i = 0; i < AL; i++)
      gload16(gA + (size_t)(i * 64) * Kstride + k0, &As[slot][(i * 4 + wave) * 512]);
#pragma unroll
    for (int j = 0; j < BL; j++)
      gload16(gB + (size_t)(j * 64) * Kstride + k0, &Bs[slot][(j * 4 + wave) * 512]);
  };

  f32x4 acc[FM][FN];
  const f32x4 zero = { 0.f, 0.f, 0.f, 0.f };
#pragma unroll
  for (int i = 0; i < FM; i++)
#pragma unroll
    for (int j = 0; j < FN; j++) acc[i][j] = zero;

  int nt = Klen / 32;
#pragma unroll
  for (int p = 0; p < DEPTH - 1; p++) STAGE(p, p);

  int slot = 0, stage_slot = DEPTH - 1;
  for (int tI = 0; tI < nt; ++tI) {
    int rem = nt - 1 - tI;
    if constexpr (AL + BL == 4) {
      if (rem >= 2)      asm volatile("s_waitcnt vmcnt(8)" ::: "memory");
      else if (rem == 1) asm volatile("s_waitcnt vmcnt(4)" ::: "memory");
      else               asm volatile("s_waitcnt vmcnt(0)" ::: "memory");
    } else {             // AL+BL==3 (64x128)
      if (rem >= 2)      asm volatile("s_waitcnt vmcnt(6)" ::: "memory");
      else if (rem == 1) asm volatile("s_waitcnt vmcnt(3)" ::: "memory");
      else               asm volatile("s_waitcnt vmcnt(0)" ::: "memory");
    }
    __builtin_amdgcn_s_barrier();
    __builtin_amdgcn_sched_barrier(0);

    if (tI + DEPTH - 1 < nt) STAGE(stage_slot, tI + DEPTH - 1);

    bf16x8 af[FM], bfr[FN];
#pragma unroll
    for (int mf = 0; mf < FM; mf++)
      af[mf] = *(const bf16x8*)&As[slot][(wm * (BM / 2) + mf * 16 + lrow) * 32 + lgrp * 8];
#pragma unroll
    for (int nf = 0; nf < FN; nf++)
      bfr[nf] = *(const bf16x8*)&Bs[slot][(wn * (BN / 2) + nf * 16 + lrow) * 32 + lgrp * 8];

    __builtin_amdgcn_s_setprio(1);
#pragma unroll
    for (int mf = 0; mf < FM; mf++)
#pragma unroll
      for (int nf = 0; nf < FN; nf++)
        acc[mf][nf] = __builtin_amdgcn_mfma_f32_16x16x32_bf16(af[mf], bfr[nf], acc[mf][nf], 0, 0, 0);
    __builtin_amdgcn_s_setprio(0);

    slot = (slot + 1 == DEPTH) ? 0 : slot + 1;
    stage_slot = (stage_slot + 1 == DEPTH) ? 0 : stage_slot + 1;
  }

#pragma unroll
  for (int mf = 0; mf < FM; mf++)
#pragma unroll
    for (int nf = 0; nf < FN; nf++)
#pragma unroll
      for (int r = 0; r < 4; r++) {
        int row = m0 + wm * (BM / 2) + mf * 16 + lgrp * 4 + r;
        int col = n0 + wn * (BN / 2) + nf * 16 + lrow;
        float v = acc[mf][nf][r];
        if (EPI == 0) {
          out16[(size_t)row * N + col] = f2b(v * scale);
        } else if (EPI == 1) {
          out32[(size_t)row * N + col] = v + res[(size_t)row * N + col];
        } else {   // EPI 3: split-K partial
          out32[(size_t)blockIdx.z * M * N + (size_t)row * N + col] = v;
        }
      }
}

// --------------- Wff1 fused SwiGLU, m201-style 8-phase (dual) ---------------
// act[4096,4096] = silu(yn@Wg)*(yn@Wv); Wff1T stored [8192][1024] (val rows
// 0..4095, gate 4096..8191). BM=256, BN=128 (val)+128 (gate), BK=64,
// 512 thr (8 waves 2Mx4N), double-buffered 128KB LDS, 128B rows with 3-bit
// XOR swizzle: LDS[row][c16] = global[row][c16 ^ (row&7)] via pre-swizzled
// gload source; ds_read uses chunk = (kh*4+lgrp) ^ (row&7)  -> conflict-free.
// 4 phases/K-step: {ds_reads | prefetch gloads | bar | lgkm0 | 16 MFMA | bar}.
__global__ __launch_bounds__(512, 2) void gemm_ff1(
    const short* __restrict__ A, const short* __restrict__ B,
    short* __restrict__ out16)
{
  constexpr int K = 1024, NT = 16;   // 16 K-steps of 64
  __shared__ __align__(16) short As[2][256 * 64];   // 64 KB
  __shared__ __align__(16) short Bv[2][128 * 64];   // 32 KB
  __shared__ __align__(16) short Bg[2][128 * 64];   // 32 KB

  int t = threadIdx.x;
  int lane = t & 63, wave = t >> 6;
  int wm = wave >> 2, wn = wave & 3;          // 2M x 4N
  int lrow = lane & 15, lgrp = lane >> 4;
  int m0 = blockIdx.y * 256, n0 = blockIdx.x * 128;

  // staging: one gload line/wave = 8 rows x 128B. lane l -> row +(l>>3),
  // 16B chunk l&7 (linear LDS). Source chunk pre-swizzled: (l&7)^(l>>3).
  int srow8 = lane >> 3;
  int schunk = ((lane & 7) ^ srow8) * 8;
  const short* gA  = A + (size_t)(m0 + wave * 8 + srow8) * K + schunk;
  const short* gBv = B + (size_t)(n0 + wave * 8 + srow8) * K + schunk;
  const short* gBg = B + (size_t)(4096 + n0 + wave * 8 + srow8) * K + schunk;

  f32x4 acc[8][2], acc2[8][2];
  const f32x4 zero = { 0.f, 0.f, 0.f, 0.f };
#pragma unroll
  for (int i = 0; i < 8; i++) {
    acc[i][0] = zero; acc[i][1] = zero; acc2[i][0] = zero; acc2[i][1] = zero;
  }

  // swizzled ds_read chunk offsets (shorts): ((kh*4+lgrp) ^ (lrow&7)) * 8
  int rc0 = ((lgrp) ^ (lrow & 7)) * 8;          // kh = 0
  int rc1 = ((4 | lgrp) ^ (lrow & 7)) * 8;      // kh = 1

  // prologue: stage tile 0 fully (8 lines)
#pragma unroll
  for (int i = 0; i < 4; i++)
    gload16(gA + (size_t)(i * 64) * K, &As[0][(i * 64 + wave * 8) * 64]);
#pragma unroll
  for (int j = 0; j < 2; j++) {
    gload16(gBv + (size_t)(j * 64) * K, &Bv[0][(j * 64 + wave * 8) * 64]);
    gload16(gBg + (size_t)(j * 64) * K, &Bg[0][(j * 64 + wave * 8) * 64]);
  }
  asm volatile("s_waitcnt vmcnt(0)" ::: "memory");
  __builtin_amdgcn_s_barrier();
  __builtin_amdgcn_sched_barrier(0);

  for (int tI = 0; tI < NT; ++tI) {
    int cur = tI & 1, nxt = cur ^ 1;
    bool pf = (tI + 1 < NT);
    int kn = (tI + 1) * 64;
    bf16x8 af0[8], af1[8], bvf[2], bgf[2];

    // ---------------- phase 0: val, k-half 0 -------------------------------
#pragma unroll
    for (int mf = 0; mf < 8; mf++)
      af0[mf] = *(const bf16x8*)&As[cur][(wm * 128 + mf * 16 + lrow) * 64 + rc0];
    bvf[0] = *(const bf16x8*)&Bv[cur][(wn * 32 + lrow) * 64 + rc0];
    bvf[1] = *(const bf16x8*)&Bv[cur][(wn * 32 + 16 + lrow) * 64 + rc0];
    if (pf) {
      gload16(gA + kn,                     &As[nxt][(wave * 8) * 64]);
      gload16(gA + (size_t)64 * K + kn,    &As[nxt][(64 + wave * 8) * 64]);
      gload16(gA + (size_t)128 * K + kn,   &As[nxt][(128 + wave * 8) * 64]);
    }
    __builtin_amdgcn_s_barrier();
    asm volatile("s_waitcnt lgkmcnt(0)" ::: "memory");
    __builtin_amdgcn_sched_barrier(0);
    __builtin_amdgcn_s_setprio(1);
#pragma unroll
    for (int mf = 0; mf < 8; mf++) {
      acc[mf][0] = __builtin_amdgcn_mfma_f32_16x16x32_bf16(af0[mf], bvf[0], acc[mf][0], 0, 0, 0);
      acc[mf][1] = __builtin_amdgcn_mfma_f32_16x16x32_bf16(af0[mf], bvf[1], acc[mf][1], 0, 0, 0);
    }
    __builtin_amdgcn_s_setprio(0);
    __builtin_amdgcn_s_barrier();
    __builtin_amdgcn_sched_barrier(0);

    // ---------------- phase 1: val, k-half 1 -------------------------------
#pragma unroll
    for (int mf = 0; mf < 8; mf++)
      af1[mf] = *(const bf16x8*)&As[cur][(wm * 128 + mf * 16 + lrow) * 64 + rc1];
    bvf[0] = *(const bf16x8*)&Bv[cur][(wn * 32 + lrow) * 64 + rc1];
    bvf[1] = *(const bf16x8*)&Bv[cur][(wn * 32 + 16 + lrow) * 64 + rc1];
    if (pf) {
      gload16(gA + (size_t)192 * K + kn,   &As[nxt][(192 + wave * 8) * 64]);
      gload16(gBv + kn,                    &Bv[nxt][(wave * 8) * 64]);
      gload16(gBv + (size_t)64 * K + kn,   &Bv[nxt][(64 + wave * 8) * 64]);
    }
    __builtin_amdgcn_s_barrier();
    asm volatile("s_waitcnt lgkmcnt(0)" ::: "memory");
    __builtin_amdgcn_sched_barrier(0);
    __builtin_amdgcn_s_setprio(1);
#pragma unroll
    for (int mf = 0; mf < 8; mf++) {
      acc[mf][0] = __builtin_amdgcn_mfma_f32_16x16x32_bf16(af1[mf], bvf[0], acc[mf][0], 0, 0, 0);
      acc[mf][1] = __builtin_amdgcn_mfma_f32_16x16x32_bf16(af1[mf], bvf[1], acc[mf][1], 0, 0, 0);
    }
    __builtin_amdgcn_s_setprio(0);
    __builtin_amdgcn_s_barrier();
    __builtin_amdgcn_sched_barrier(0);

    // ---------------- phase 2: gate, k-half 0 ------------------------------
    bgf[0] = *(const bf16x8*)&Bg[cur][(wn * 32 + lrow) * 64 + rc0];
    bgf[1] = *(const bf16x8*)&Bg[cur][(wn * 32 + 16 + lrow) * 64 + rc0];
    if (pf) {
      gload16(gBg + kn,                    &Bg[nxt][(wave * 8) * 64]);
      gload16(gBg + (size_t)64 * K + kn,   &Bg[nxt][(64 + wave * 8) * 64]);
    }
    __builtin_amdgcn_s_barrier();
    asm volatile("s_waitcnt lgkmcnt(0)" ::: "memory");
    __builtin_amdgcn_sched_barrier(0);
    __builtin_amdgcn_s_setprio(1);
#pragma unroll
    for (int mf = 0; mf < 8; mf++) {
      acc2[mf][0] = __builtin_amdgcn_mfma_f32_16x16x32_bf16(af0[mf], bgf[0], acc2[mf][0], 0, 0, 0);
      acc2[mf][1] = __builtin_amdgcn_mfma_f32_16x16x32_bf16(af0[mf], bgf[1], acc2[mf][1], 0, 0, 0);
    }
    __builtin_amdgcn_s_setprio(0);
    __builtin_amdgcn_s_barrier();
    __builtin_amdgcn_sched_barrier(0);

    // ---------------- phase 3: gate, k-half 1 (no prefetch) ----------------
    bgf[0] = *(const bf16x8*)&Bg[cur][(wn * 32 + lrow) * 64 + rc1];
    bgf[1] = *(const bf16x8*)&Bg[cur][(wn * 32 + 16 + lrow) * 64 + rc1];
    __builtin_amdgcn_s_barrier();
    asm volatile("s_waitcnt lgkmcnt(0)" ::: "memory");
    __builtin_amdgcn_sched_barrier(0);
    __builtin_amdgcn_s_setprio(1);
#pragma unroll
    for (int mf = 0; mf < 8; mf++) {
      acc2[mf][0] = __builtin_amdgcn_mfma_f32_16x16x32_bf16(af1[mf], bgf[0], acc2[mf][0], 0, 0, 0);
      acc2[mf][1] = __builtin_amdgcn_mfma_f32_16x16x32_bf16(af1[mf], bgf[1], acc2[mf][1], 0, 0, 0);
    }
    __builtin_amdgcn_s_setprio(0);
    __builtin_amdgcn_s_barrier();
    __builtin_amdgcn_sched_barrier(0);

    // end of step: tile t+1's loads (issued phases 0-2, >=1.5 phases ago)
    asm volatile("s_waitcnt vmcnt(0)" ::: "memory");
    __builtin_amdgcn_s_barrier();
    __builtin_amdgcn_sched_barrier(0);
  }

  // epilogue: act = silu(gate) * val
#pragma unroll
  for (int mf = 0; mf < 8; mf++)
#pragma unroll
    for (int nf = 0; nf < 2; nf++)
#pragma unroll
      for (int r = 0; r < 4; r++) {
        int row = m0 + wm * 128 + mf * 16 + lgrp * 4 + r;
        int col = n0 + wn * 32 + nf * 16 + lrow;
        float v = acc[mf][nf][r];
        float gate = acc2[mf][nf][r];
        float sig = 1.0f / (1.0f + __expf(-gate));
        out16[(size_t)row * 4096 + col] = f2b(v * gate * sig);
      }
}

// ---------------- split-K reduce: kv16 = bf16(sum_z partial[z]) ------------
__global__ __launch_bounds__(256) void kvred_kernel(const float* __restrict__ p,
                                                    short* __restrict__ out, int n4) {
  int i = blockIdx.x * 256 + threadIdx.x;
  if (i >= n4) return;
  const int S = 4096 * 128 / 4;
  float4 a = ((const float4*)p)[i];
  float4 b = ((const float4*)p)[i + S];
  float4 c = ((const float4*)p)[i + 2 * S];
  float4 d = ((const float4*)p)[i + 3 * S];
  s16x4 o = { f2b(a.x + b.x + c.x + d.x), f2b(a.y + b.y + c.y + d.y),
              f2b(a.z + b.z + c.z + d.z), f2b(a.w + b.w + c.w + d.w) };
  ((s16x4*)out)[i] = o;
}

// ------------------------------- Attention ---------------------------------
// MQA flash attention. QBLK=32/wave; 4 waves/block share swizzled K/V tiles.
// Raw-barrier pipeline: per KV tile, loads for tile j+1 are issued right
// after the LDS write of tile j and stay in flight through the whole
// compute phase (no vmcnt drain at any barrier). No min-waves bound:
// VGPR must stay ~144 (spills at 64 were a 3.4x regression, round 11).
__global__ __launch_bounds__(256) void attn_kernel(const short* __restrict__ q,
                                                   const short* __restrict__ kv,
                                                   short* __restrict__ ao)
{
  __shared__ __align__(16) short Ks[64 * 64];      // [kv][d]   swizzled
  __shared__ __align__(16) short Vs[64 * 64];      // [d][kv]   swizzled
  __shared__ __align__(16) short Ps[4][32 * 64];   // per-wave [q][kv] swizzled

  int t = threadIdx.x;
  int lane = t & 63, wave = t >> 6;
  int lrow = lane & 15, lgrp = lane >> 4;
  int qt = blockIdx.x;
  int b = blockIdx.y >> 2, hg = blockIdx.y & 3;
  int h = hg * 4 + wave;

  char* Kb = (char*)Ks;
  char* Vb = (char*)Vs;
  char* Pb = (char*)Ps + wave * (32 * 64 * 2);

  bf16x8 qf[2][2];
  const short* qb = q + ((size_t)(b * 1024 + qt * 32)) * 1024 + h * 64;
#pragma unroll
  for (int mf = 0; mf < 2; mf++)
#pragma unroll
    for (int kk = 0; kk < 2; kk++)
      qf[mf][kk] = *(const bf16x8*)&qb[(size_t)(mf * 16 + lrow) * 1024 + kk * 32 + lgrp * 8];

  f32x4 oacc[2][4];
  float m_[2][4], l_[2][4];
  const f32x4 zero = { 0.f, 0.f, 0.f, 0.f };
#pragma unroll
  for (int i = 0; i < 2; i++)
#pragma unroll
    for (int j = 0; j < 4; j++) { oacc[i][j] = zero; }
#pragma unroll
  for (int i = 0; i < 2; i++)
#pragma unroll
    for (int r = 0; r < 4; r++) { m_[i][r] = -3.0e38f; l_[i][r] = 0.f; }

  // prologue: issue KV tile 0 loads (land at first loop-top vmcnt)
  int4 d[4];
  {
    const short* kvb = kv + ((size_t)(b * 1024 + lane)) * 128 + wave * 32;
#pragma unroll
    for (int i = 0; i < 4; i++) d[i] = ((const int4*)kvb)[i];
  }

  for (int j0 = 0; j0 < 1024; j0 += 64) {
    __builtin_amdgcn_s_barrier();        // all waves done reading prev K/V
    __builtin_amdgcn_sched_barrier(0);
    asm volatile("s_waitcnt vmcnt(0)" ::: "memory");   // d[] arrived
    if (wave < 2) {
      int sw = (lane & 7) << 4;
#pragma unroll
      for (int i = 0; i < 4; i++)
        *(int4*)(Kb + lane * 128 + ((wave * 64 + i * 16) ^ sw)) = d[i];
    } else {
#pragma unroll
      for (int i = 0; i < 4; i++) {
        union { int4 v; short s[8]; } u; u.v = d[i];
#pragma unroll
        for (int j = 0; j < 8; j++) {
          int dd = (wave - 2) * 32 + i * 8 + j;
          *(short*)(Vb + dd * 128 + ((lane * 2) ^ ((dd & 7) << 4))) = u.s[j];
        }
      }
    }
    // issue next tile's loads; they stay in flight through compute
    if (j0 + 64 < 1024) {
      const short* kvn = kv + ((size_t)(b * 1024 + j0 + 64 + lane)) * 128 + wave * 32;
#pragma unroll
      for (int i = 0; i < 4; i++) d[i] = ((const int4*)kvn)[i];
    }
    asm volatile("s_waitcnt lgkmcnt(0)" ::: "memory");  // LDS writes visible
    __builtin_amdgcn_s_barrier();
    __builtin_amdgcn_sched_barrier(0);

    // ---- S = Q @ K^T ----
    bf16x8 kf[4][2];
#pragma unroll
    for (int nf = 0; nf < 4; nf++) {
      int row = nf * 16 + lrow, sw = (row & 7) << 4;
      kf[nf][0] = *(const bf16x8*)(Kb + row * 128 + ((lgrp * 16) ^ sw));
      kf[nf][1] = *(const bf16x8*)(Kb + row * 128 + ((64 + lgrp * 16) ^ sw));
    }
    f32x4 sacc[2][4];
#pragma unroll
    for (int i = 0; i < 2; i++)
#pragma unroll
      for (int j = 0; j < 4; j++) sacc[i][j] = zero;
    __builtin_amdgcn_s_setprio(1);
#pragma unroll
    for (int mf = 0; mf < 2; mf++)
#pragma unroll
      for (int nf = 0; nf < 4; nf++)
#pragma unroll
        for (int kk = 0; kk < 2; kk++)
          sacc[mf][nf] = __builtin_amdgcn_mfma_f32_16x16x32_bf16(qf[mf][kk], kf[nf][kk], sacc[mf][nf], 0, 0, 0);
    __builtin_amdgcn_s_setprio(0);

    // ---- online softmax with defer-max (T13) ----
    float pmax[2][4];
    bool okd = true;
#pragma unroll
    for (int mf = 0; mf < 2; mf++)
#pragma unroll
      for (int r = 0; r < 4; r++) {
        float pm = fmaxf(fmaxf(sacc[mf][0][r], sacc[mf][1][r]),
                         fmaxf(sacc[mf][2][r], sacc[mf][3][r]));
        pmax[mf][r] = pm;
        okd = okd && (pm <= m_[mf][r] + 8.0f);
      }
    if (__all(okd)) {
#pragma unroll
      for (int mf = 0; mf < 2; mf++)
#pragma unroll
        for (int r = 0; r < 4; r++) {
          int row = mf * 16 + lgrp * 4 + r, sw = (row & 7) << 4;
          float al = 0.f;
#pragma unroll
          for (int nf = 0; nf < 4; nf++) {
            float p = __expf(sacc[mf][nf][r] - m_[mf][r]);
            *(short*)(Pb + row * 128 + (((nf * 16 + lrow) * 2) ^ sw)) = f2b(p);
            al += p;
          }
          l_[mf][r] += al;
        }
    } else {
#pragma unroll
      for (int mf = 0; mf < 2; mf++)
#pragma unroll
        for (int r = 0; r < 4; r++) {
          float mx = pmax[mf][r];
#pragma unroll
          for (int o = 8; o >= 1; o >>= 1) mx = fmaxf(mx, __shfl_xor(mx, o));
          float mnew = fmaxf(m_[mf][r], mx);
          float corr = __expf(m_[mf][r] - mnew);
          int row = mf * 16 + lgrp * 4 + r, sw = (row & 7) << 4;
          float al = 0.f;
#pragma unroll
          for (int nf = 0; nf < 4; nf++) {
            float p = __expf(sacc[mf][nf][r] - mnew);
            *(short*)(Pb + row * 128 + (((nf * 16 + lrow) * 2) ^ sw)) = f2b(p);
            al += p;
          }
          l_[mf][r] = l_[mf][r] * corr + al;
          m_[mf][r] = mnew;
#pragma unroll
          for (int nf = 0; nf < 4; nf++) oacc[mf][nf][r] *= corr;
        }
    }

    // ---- O += P @ V ----  (P is wave-private: no barrier needed)
    bf16x8 vf[4][2], pfr[2][2];
#pragma unroll
    for (int nf = 0; nf < 4; nf++) {
      int row = nf * 16 + lrow, sw = (row & 7) << 4;
      vf[nf][0] = *(const bf16x8*)(Vb + row * 128 + ((lgrp * 16) ^ sw));
      vf[nf][1] = *(const bf16x8*)(Vb + row * 128 + ((64 + lgrp * 16) ^ sw));
    }
#pragma unroll
    for (int mf = 0; mf < 2; mf++) {
      int row = mf * 16 + lrow, sw = (row & 7) << 4;
      pfr[mf][0] = *(const bf16x8*)(Pb + row * 128 + ((lgrp * 16) ^ sw));
      pfr[mf][1] = *(const bf16x8*)(Pb + row * 128 + ((64 + lgrp * 16) ^ sw));
    }
    __builtin_amdgcn_s_setprio(1);
#pragma unroll
    for (int mf = 0; mf < 2; mf++)
#pragma unroll
      for (int nf = 0; nf < 4; nf++)
#pragma unroll
        for (int kk = 0; kk < 2; kk++)
          oacc[mf][nf] = __builtin_amdgcn_mfma_f32_16x16x32_bf16(pfr[mf][kk], vf[nf][kk], oacc[mf][nf], 0, 0, 0);
    __builtin_amdgcn_s_setprio(0);
  }

  // final l reduction + write
#pragma unroll
  for (int mf = 0; mf < 2; mf++)
#pragma unroll
    for (int r = 0; r < 4; r++) {
      float ls = l_[mf][r];
#pragma unroll
      for (int o = 8; o >= 1; o >>= 1) ls += __shfl_xor(ls, o);
      float inv = 1.0f / ls;
      int qrow = qt * 32 + mf * 16 + lgrp * 4 + r;
#pragma unroll
      for (int nf = 0; nf < 4; nf++) {
        float val = oacc[mf][nf][r] * inv;
        ao[((size_t)(b * 1024 + qrow)) * 1024 + h * 64 + nf * 16 + lrow] = f2b(val);
      }
    }
}

// ------------------------------- launcher ----------------------------------
extern "C" void kernel_launch(void* const* d_in, const int* in_sizes, int n_in,
                              void* d_out, int out_size, void* d_ws, size_t ws_size,
                              hipStream_t stream) {
  const float* x     = (const float*)d_in[0];
  const float* y     = (const float*)d_in[1];
  const float* g1    = (const float*)d_in[2];
  const float* g2    = (const float*)d_in[3];
  const float* g_out = (const float*)d_in[4];
  const float* Wq    = (const float*)d_in[5];
  const float* Wkv   = (const float*)d_in[6];
  const float* Wo    = (const float*)d_in[7];
  const float* Wff1  = (const float*)d_in[8];
  const float* Wff2  = (const float*)d_in[9];

  char* ws = (char*)d_ws;
  size_t off = 0;
  auto alloc = [&](size_t bytes) { char* p = ws + off; off += bytes; return p; };
  short* wqT    = (short*)alloc((size_t)1024 * 1024 * 2);   // [1024][1024]
  short* wkvT   = (short*)alloc((size_t)128 * 1024 * 2);    // [128][1024]
  short* woT    = (short*)alloc((size_t)1024 * 1024 * 2);   // [1024][1024]
  short* wff1T  = (short*)alloc((size_t)8192 * 1024 * 2);   // [8192][1024]
  short* wff2T  = (short*)alloc((size_t)1024 * 4096 * 2);   // [1024][4096]
  short* xn16   = (short*)alloc((size_t)4096 * 1024 * 2);
  short* yn16   = (short*)alloc((size_t)4096 * 1024 * 2);
  float* ynf    = (float*)alloc((size_t)4096 * 1024 * 4);
  short* q16    = (short*)alloc((size_t)4096 * 1024 * 2);
  short* kv16   = (short*)alloc((size_t)4096 * 128 * 2);
  short* ao16   = (short*)alloc((size_t)4096 * 1024 * 2);
  float* lnout  = (float*)alloc((size_t)4096 * 1024 * 4);
  short* act16  = (short*)alloc((size_t)4096 * 4096 * 2);
  float* kvpart = (float*)alloc((size_t)4 * 4096 * 128 * 4);
  float* outf   = (float*)d_out;

  // weight transpose-convert: [K][N] f32 -> [N][K] bf16
  cvtT_kernel<<<dim3(1024 / 32, 1024 / 32), 256, 0, stream>>>(Wq,   wqT,   1024, 1024);
  cvtT_kernel<<<dim3(128 / 32, 1024 / 32),  256, 0, stream>>>(Wkv,  wkvT,  1024, 128);
  cvtT_kernel<<<dim3(1024 / 32, 1024 / 32), 256, 0, stream>>>(Wo,   woT,   1024, 1024);
  cvtT_kernel<<<dim3(8192 / 32, 1024 / 32), 256, 0, stream>>>(Wff1, wff1T, 1024, 8192);
  cvtT_kernel<<<dim3(1024 / 32, 4096 / 32), 256, 0, stream>>>(Wff2, wff2T, 4096, 1024);

  // LayerNorms
  ln_kernel<<<4096, 256, 0, stream>>>(x, g1, xn16, nullptr);
  ln_kernel<<<4096, 256, 0, stream>>>(y, g2, yn16, ynf);

  // q = (xn @ Wq) * 1/8   [BM=64: 512 blocks]
  gemm_ring<0, 64, 128><<<dim3(8, 64), 256, 0, stream>>>(
      xn16, wqT, 4096, 1024, 1024, 1024, q16, nullptr, nullptr, 0.125f);
  // kv = yn @ Wkv   [split-K x4; f32 partials]
  gemm_ring<3, 64, 128><<<dim3(1, 64, 4), 256, 0, stream>>>(
      yn16, wkvT, 4096, 128, 1024, 256, nullptr, kvpart, nullptr, 1.0f);
  kvred_kernel<<<512, 256, 0, stream>>>(kvpart, kv16, 4096 * 128 / 4);

  // attention
  attn_kernel<<<dim3(32, 16), 256, 0, stream>>>(q16, kv16, ao16);

  // out = attn @ Wo + yn   (f32, into d_out as scratch)
  gemm_ring<1, 64, 128><<<dim3(8, 64), 256, 0, stream>>>(
      ao16, woT, 4096, 1024, 1024, 1024, nullptr, outf, ynf, 1.0f);

  // ln_out = LN(out) * g_out  (f32)
  ln_kernel<<<4096, 256, 0, stream>>>(outf, g_out, nullptr, lnout);

  // act = silu(gate) * val   (m201-style 8-phase fused SwiGLU GEMM)
  gemm_ff1<<<dim3(32, 16), 512, 0, stream>>>(yn16, wff1T, act16);

  // d_out = act @ Wff2 + ln_out
  gemm_ring<1, 64, 128><<<dim3(8, 64), 256, 0, stream>>>(
      act16, wff2T, 4096, 1024, 4096, 4096, nullptr, outf, lnout, 1.0f);
}

// Round 13
// 286.395 us; speedup vs baseline: 1.9723x; 1.1058x over previous
//
#include <hip/hip_runtime.h>
#include <hip/hip_bf16.h>

// ---------------------------------------------------------------------------
// MQ Parallel-FF Transformer block, MI355X (gfx950)
// Round 13: attention restructure — V^T materialized globally by kvred
//           (512KB), K and V^T tiles staged via global_load_lds with the
//           ff1-proven XOR swizzle, double-buffered + counted vmcnt(4),
//           no scalar V transpose, uniform work across waves.
//           Everything else unchanged from round 12.
// ---------------------------------------------------------------------------

typedef __attribute__((ext_vector_type(8))) short bf16x8;   // 8 bf16 (4 VGPR)
typedef __attribute__((ext_vector_type(4))) short s16x4;
typedef __attribute__((ext_vector_type(4))) float f32x4;

__device__ __forceinline__ short f2b(float f) {
  union { float f; unsigned u; } v; v.f = f;
  unsigned r = (v.u + 0x7fffu + ((v.u >> 16) & 1u)) >> 16;
  return (short)r;
}

__device__ __forceinline__ void gload16(const short* g, short* l) {
  __builtin_amdgcn_global_load_lds(
      (const __attribute__((address_space(1))) void*)g,
      (__attribute__((address_space(3))) void*)l, 16, 0, 0);
}

// ---------------- f32 [K][N] -> bf16 [N][K] transpose-convert ---------------
__global__ __launch_bounds__(256) void cvtT_kernel(const float* __restrict__ in,
                                                   short* __restrict__ out,
                                                   int K, int N) {
  __shared__ float tile[32][33];
  int n0 = blockIdx.x * 32, k0 = blockIdx.y * 32;
  int tx = threadIdx.x & 7, ty = threadIdx.x >> 3;     // 8 x 32
  float4 v = *(const float4*)&in[(size_t)(k0 + ty) * N + n0 + tx * 4];
  tile[ty][tx * 4 + 0] = v.x;
  tile[ty][tx * 4 + 1] = v.y;
  tile[ty][tx * 4 + 2] = v.z;
  tile[ty][tx * 4 + 3] = v.w;
  __syncthreads();
  s16x4 o = { f2b(tile[tx * 4 + 0][ty]), f2b(tile[tx * 4 + 1][ty]),
              f2b(tile[tx * 4 + 2][ty]), f2b(tile[tx * 4 + 3][ty]) };
  *(s16x4*)&out[(size_t)(n0 + ty) * K + k0 + tx * 4] = o;
}

// --------------------------------- LayerNorm -------------------------------
__global__ __launch_bounds__(256) void ln_kernel(const float* __restrict__ in,
                                                 const float* __restrict__ gamma,
                                                 short* __restrict__ out16,
                                                 float* __restrict__ out32) {
  int row = blockIdx.x;
  int t = threadIdx.x;
  float4 v = ((const float4*)(in + (size_t)row * 1024))[t];
  float s  = v.x + v.y + v.z + v.w;
  float sq = v.x*v.x + v.y*v.y + v.z*v.z + v.w*v.w;
  __shared__ float ssum[256], ssq[256];
  ssum[t] = s; ssq[t] = sq;
  __syncthreads();
  for (int o = 128; o > 0; o >>= 1) {
    if (t < o) { ssum[t] += ssum[t + o]; ssq[t] += ssq[t + o]; }
    __syncthreads();
  }
  float mu  = ssum[0] * (1.0f / 1024.0f);
  float var = ssq[0] * (1.0f / 1024.0f) - mu * mu;
  float rs  = rsqrtf(var + 1e-5f);
  float4 g = ((const float4*)gamma)[t];
  float o0 = (v.x - mu) * rs * g.x;
  float o1 = (v.y - mu) * rs * g.y;
  float o2 = (v.z - mu) * rs * g.z;
  float o3 = (v.w - mu) * rs * g.w;
  if (out16) {
    s16x4 o = { f2b(o0), f2b(o1), f2b(o2), f2b(o3) };
    ((s16x4*)out16)[(size_t)row * 256 + t] = o;
  }
  if (out32) {
    float4 o = { o0, o1, o2, o3 };
    ((float4*)out32)[(size_t)row * 256 + t] = o;
  }
}

// ------------------------------- GEMM (ring) -------------------------------
// C[M,N] = A[M,K] @ B^T, B stored [N][Kstride] bf16. BMxBN tile, BK=32,
// 256 thr (4 waves 2x2), ring DEPTH=4, counted vmcnt, 1 barrier/K-tile.
template<int EPI, int BM, int BN>
__global__ __launch_bounds__(256, 2) void gemm_ring(
    const short* __restrict__ A, const short* __restrict__ B,
    int M, int N, int Kstride, int Klen,
    short* __restrict__ out16, float* __restrict__ out32,
    const float* __restrict__ res, float scale)
{
  constexpr int DEPTH = 4;
  constexpr int FM = BM / 32;
  constexpr int FN = BN / 32;
  constexpr int AL = BM / 64;
  constexpr int BL = BN / 64;
  __shared__ __align__(16) short As[DEPTH][BM * 32];
  __shared__ __align__(16) short Bs[DEPTH][BN * 32];

  int t = threadIdx.x;
  int lane = t & 63, wave = t >> 6;
  int wm = wave >> 1, wn = wave & 1;
  int lrow = lane & 15, lgrp = lane >> 4;
  int m0 = blockIdx.y * BM, n0 = blockIdx.x * BN;
  int kbase = blockIdx.z * Klen;

  int srow = lane >> 2, scol = (lane & 3) * 8;
  const short* gA = A + (size_t)(m0 + wave * 16 + srow) * Kstride + kbase + scol;
  const short* gB = B + (size_t)(n0 + wave * 16 + srow) * Kstride + kbase + scol;

  auto STAGE = [&](int slot, int kt) {
    int k0 = kt * 32;
#pragma unroll
    for (int i = 0; i < AL; i++)
      gload16(gA + (size_t)(i * 64) * Kstride + k0, &As[slot][(i * 4 + wave) * 512]);
#pragma unroll
    for (int j = 0; j < BL; j++)
      gload16(gB + (size_t)(j * 64) * Kstride + k0, &Bs[slot][(j * 4 + wave) * 512]);
  };

  f32x4 acc[FM][FN];
  const f32x4 zero = { 0.f, 0.f, 0.f, 0.f };
#pragma unroll
  for (int i = 0; i < FM; i++)
#pragma unroll
    for (int j = 0; j < FN; j++) acc[i][j] = zero;

  int nt = Klen / 32;
#pragma unroll
  for (int p = 0; p < DEPTH - 1; p++) STAGE(p, p);

  int slot = 0, stage_slot = DEPTH - 1;
  for (int tI = 0; tI < nt; ++tI) {
    int rem = nt - 1 - tI;
    if constexpr (AL + BL == 4) {
      if (rem >= 2)      asm volatile("s_waitcnt vmcnt(8)" ::: "memory");
      else if (rem == 1) asm volatile("s_waitcnt vmcnt(4)" ::: "memory");
      else               asm volatile("s_waitcnt vmcnt(0)" ::: "memory");
    } else {             // AL+BL==3 (64x128)
      if (rem >= 2)      asm volatile("s_waitcnt vmcnt(6)" ::: "memory");
      else if (rem == 1) asm volatile("s_waitcnt vmcnt(3)" ::: "memory");
      else               asm volatile("s_waitcnt vmcnt(0)" ::: "memory");
    }
    __builtin_amdgcn_s_barrier();
    __builtin_amdgcn_sched_barrier(0);

    if (tI + DEPTH - 1 < nt) STAGE(stage_slot, tI + DEPTH - 1);

    bf16x8 af[FM], bfr[FN];
#pragma unroll
    for (int mf = 0; mf < FM; mf++)
      af[mf] = *(const bf16x8*)&As[slot][(wm * (BM / 2) + mf * 16 + lrow) * 32 + lgrp * 8];
#pragma unroll
    for (int nf = 0; nf < FN; nf++)
      bfr[nf] = *(const bf16x8*)&Bs[slot][(wn * (BN / 2) + nf * 16 + lrow) * 32 + lgrp * 8];

    __builtin_amdgcn_s_setprio(1);
#pragma unroll
    for (int mf = 0; mf < FM; mf++)
#pragma unroll
      for (int nf = 0; nf < FN; nf++)
        acc[mf][nf] = __builtin_amdgcn_mfma_f32_16x16x32_bf16(af[mf], bfr[nf], acc[mf][nf], 0, 0, 0);
    __builtin_amdgcn_s_setprio(0);

    slot = (slot + 1 == DEPTH) ? 0 : slot + 1;
    stage_slot = (stage_slot + 1 == DEPTH) ? 0 : stage_slot + 1;
  }

#pragma unroll
  for (int mf = 0; mf < FM; mf++)
#pragma unroll
    for (int nf = 0; nf < FN; nf++)
#pragma unroll
      for (int r = 0; r < 4; r++) {
        int row = m0 + wm * (BM / 2) + mf * 16 + lgrp * 4 + r;
        int col = n0 + wn * (BN / 2) + nf * 16 + lrow;
        float v = acc[mf][nf][r];
        if (EPI == 0) {
          out16[(size_t)row * N + col] = f2b(v * scale);
        } else if (EPI == 1) {
          out32[(size_t)row * N + col] = v + res[(size_t)row * N + col];
        } else {   // EPI 3: split-K partial
          out32[(size_t)blockIdx.z * M * N + (size_t)row * N + col] = v;
        }
      }
}

// --------------- Wff1 fused SwiGLU, m201-style 8-phase (dual) ---------------
__global__ __launch_bounds__(512, 2) void gemm_ff1(
    const short* __restrict__ A, const short* __restrict__ B,
    short* __restrict__ out16)
{
  constexpr int K = 1024, NT = 16;   // 16 K-steps of 64
  __shared__ __align__(16) short As[2][256 * 64];   // 64 KB
  __shared__ __align__(16) short Bv[2][128 * 64];   // 32 KB
  __shared__ __align__(16) short Bg[2][128 * 64];   // 32 KB

  int t = threadIdx.x;
  int lane = t & 63, wave = t >> 6;
  int wm = wave >> 2, wn = wave & 3;          // 2M x 4N
  int lrow = lane & 15, lgrp = lane >> 4;
  int m0 = blockIdx.y * 256, n0 = blockIdx.x * 128;

  int srow8 = lane >> 3;
  int schunk = ((lane & 7) ^ srow8) * 8;
  const short* gA  = A + (size_t)(m0 + wave * 8 + srow8) * K + schunk;
  const short* gBv = B + (size_t)(n0 + wave * 8 + srow8) * K + schunk;
  const short* gBg = B + (size_t)(4096 + n0 + wave * 8 + srow8) * K + schunk;

  f32x4 acc[8][2], acc2[8][2];
  const f32x4 zero = { 0.f, 0.f, 0.f, 0.f };
#pragma unroll
  for (int i = 0; i < 8; i++) {
    acc[i][0] = zero; acc[i][1] = zero; acc2[i][0] = zero; acc2[i][1] = zero;
  }

  int rc0 = ((lgrp) ^ (lrow & 7)) * 8;          // kh = 0
  int rc1 = ((4 | lgrp) ^ (lrow & 7)) * 8;      // kh = 1

#pragma unroll
  for (int i = 0; i < 4; i++)
    gload16(gA + (size_t)(i * 64) * K, &As[0][(i * 64 + wave * 8) * 64]);
#pragma unroll
  for (int j = 0; j < 2; j++) {
    gload16(gBv + (size_t)(j * 64) * K, &Bv[0][(j * 64 + wave * 8) * 64]);
    gload16(gBg + (size_t)(j * 64) * K, &Bg[0][(j * 64 + wave * 8) * 64]);
  }
  asm volatile("s_waitcnt vmcnt(0)" ::: "memory");
  __builtin_amdgcn_s_barrier();
  __builtin_amdgcn_sched_barrier(0);

  for (int tI = 0; tI < NT; ++tI) {
    int cur = tI & 1, nxt = cur ^ 1;
    bool pf = (tI + 1 < NT);
    int kn = (tI + 1) * 64;
    bf16x8 af0[8], af1[8], bvf[2], bgf[2];

    // ---------------- phase 0: val, k-half 0 -------------------------------
#pragma unroll
    for (int mf = 0; mf < 8; mf++)
      af0[mf] = *(const bf16x8*)&As[cur][(wm * 128 + mf * 16 + lrow) * 64 + rc0];
    bvf[0] = *(const bf16x8*)&Bv[cur][(wn * 32 + lrow) * 64 + rc0];
    bvf[1] = *(const bf16x8*)&Bv[cur][(wn * 32 + 16 + lrow) * 64 + rc0];
    if (pf) {
      gload16(gA + kn,                     &As[nxt][(wave * 8) * 64]);
      gload16(gA + (size_t)64 * K + kn,    &As[nxt][(64 + wave * 8) * 64]);
      gload16(gA + (size_t)128 * K + kn,   &As[nxt][(128 + wave * 8) * 64]);
    }
    __builtin_amdgcn_s_barrier();
    asm volatile("s_waitcnt lgkmcnt(0)" ::: "memory");
    __builtin_amdgcn_sched_barrier(0);
    __builtin_amdgcn_s_setprio(1);
#pragma unroll
    for (int mf = 0; mf < 8; mf++) {
      acc[mf][0] = __builtin_amdgcn_mfma_f32_16x16x32_bf16(af0[mf], bvf[0], acc[mf][0], 0, 0, 0);
      acc[mf][1] = __builtin_amdgcn_mfma_f32_16x16x32_bf16(af0[mf], bvf[1], acc[mf][1], 0, 0, 0);
    }
    __builtin_amdgcn_s_setprio(0);
    __builtin_amdgcn_s_barrier();
    __builtin_amdgcn_sched_barrier(0);

    // ---------------- phase 1: val, k-half 1 -------------------------------
#pragma unroll
    for (int mf = 0; mf < 8; mf++)
      af1[mf] = *(const bf16x8*)&As[cur][(wm * 128 + mf * 16 + lrow) * 64 + rc1];
    bvf[0] = *(const bf16x8*)&Bv[cur][(wn * 32 + lrow) * 64 + rc1];
    bvf[1] = *(const bf16x8*)&Bv[cur][(wn * 32 + 16 + lrow) * 64 + rc1];
    if (pf) {
      gload16(gA + (size_t)192 * K + kn,   &As[nxt][(192 + wave * 8) * 64]);
      gload16(gBv + kn,                    &Bv[nxt][(wave * 8) * 64]);
      gload16(gBv + (size_t)64 * K + kn,   &Bv[nxt][(64 + wave * 8) * 64]);
    }
    __builtin_amdgcn_s_barrier();
    asm volatile("s_waitcnt lgkmcnt(0)" ::: "memory");
    __builtin_amdgcn_sched_barrier(0);
    __builtin_amdgcn_s_setprio(1);
#pragma unroll
    for (int mf = 0; mf < 8; mf++) {
      acc[mf][0] = __builtin_amdgcn_mfma_f32_16x16x32_bf16(af1[mf], bvf[0], acc[mf][0], 0, 0, 0);
      acc[mf][1] = __builtin_amdgcn_mfma_f32_16x16x32_bf16(af1[mf], bvf[1], acc[mf][1], 0, 0, 0);
    }
    __builtin_amdgcn_s_setprio(0);
    __builtin_amdgcn_s_barrier();
    __builtin_amdgcn_sched_barrier(0);

    // ---------------- phase 2: gate, k-half 0 ------------------------------
    bgf[0] = *(const bf16x8*)&Bg[cur][(wn * 32 + lrow) * 64 + rc0];
    bgf[1] = *(const bf16x8*)&Bg[cur][(wn * 32 + 16 + lrow) * 64 + rc0];
    if (pf) {
      gload16(gBg + kn,                    &Bg[nxt][(wave * 8) * 64]);
      gload16(gBg + (size_t)64 * K + kn,   &Bg[nxt][(64 + wave * 8) * 64]);
    }
    __builtin_amdgcn_s_barrier();
    asm volatile("s_waitcnt lgkmcnt(0)" ::: "memory");
    __builtin_amdgcn_sched_barrier(0);
    __builtin_amdgcn_s_setprio(1);
#pragma unroll
    for (int mf = 0; mf < 8; mf++) {
      acc2[mf][0] = __builtin_amdgcn_mfma_f32_16x16x32_bf16(af0[mf], bgf[0], acc2[mf][0], 0, 0, 0);
      acc2[mf][1] = __builtin_amdgcn_mfma_f32_16x16x32_bf16(af0[mf], bgf[1], acc2[mf][1], 0, 0, 0);
    }
    __builtin_amdgcn_s_setprio(0);
    __builtin_amdgcn_s_barrier();
    __builtin_amdgcn_sched_barrier(0);

    // ---------------- phase 3: gate, k-half 1 (no prefetch) ----------------
    bgf[0] = *(const bf16x8*)&Bg[cur][(wn * 32 + lrow) * 64 + rc1];
    bgf[1] = *(const bf16x8*)&Bg[cur][(wn * 32 + 16 + lrow) * 64 + rc1];
    __builtin_amdgcn_s_barrier();
    asm volatile("s_waitcnt lgkmcnt(0)" ::: "memory");
    __builtin_amdgcn_sched_barrier(0);
    __builtin_amdgcn_s_setprio(1);
#pragma unroll
    for (int mf = 0; mf < 8; mf++) {
      acc2[mf][0] = __builtin_amdgcn_mfma_f32_16x16x32_bf16(af1[mf], bgf[0], acc2[mf][0], 0, 0, 0);
      acc2[mf][1] = __builtin_amdgcn_mfma_f32_16x16x32_bf16(af1[mf], bgf[1], acc2[mf][1], 0, 0, 0);
    }
    __builtin_amdgcn_s_setprio(0);
    __builtin_amdgcn_s_barrier();
    __builtin_amdgcn_sched_barrier(0);

    asm volatile("s_waitcnt vmcnt(0)" ::: "memory");
    __builtin_amdgcn_s_barrier();
    __builtin_amdgcn_sched_barrier(0);
  }

  // epilogue: act = silu(gate) * val
#pragma unroll
  for (int mf = 0; mf < 8; mf++)
#pragma unroll
    for (int nf = 0; nf < 2; nf++)
#pragma unroll
      for (int r = 0; r < 4; r++) {
        int row = m0 + wm * 128 + mf * 16 + lgrp * 4 + r;
        int col = n0 + wn * 32 + nf * 16 + lrow;
        float v = acc[mf][nf][r];
        float gate = acc2[mf][nf][r];
        float sig = 1.0f / (1.0f + __expf(-gate));
        out16[(size_t)row * 4096 + col] = f2b(v * gate * sig);
      }
}

// ------- split-K reduce: kv16 = bf16(sum_z partial[z]); also emit V^T ------
// vT[b][d][n] (d=0..63) = v-half columns of kv, transposed per batch.
__global__ __launch_bounds__(256) void kvred_kernel(const float* __restrict__ p,
                                                    short* __restrict__ out,
                                                    short* __restrict__ vT) {
  int i = blockIdx.x * 256 + threadIdx.x;
  const int S = 4096 * 128 / 4;
  float4 a = ((const float4*)p)[i];
  float4 b = ((const float4*)p)[i + S];
  float4 c = ((const float4*)p)[i + 2 * S];
  float4 d = ((const float4*)p)[i + 3 * S];
  s16x4 o = { f2b(a.x + b.x + c.x + d.x), f2b(a.y + b.y + c.y + d.y),
              f2b(a.z + b.z + c.z + d.z), f2b(a.w + b.w + c.w + d.w) };
  ((s16x4*)out)[i] = o;
  int row = i >> 5, col4 = i & 31;
  if (col4 >= 16) {          // v half: cols 64..127 -> d = col-64
    int bb = row >> 10, n = row & 1023;
    int dbase = col4 * 4 - 64;
    short* vt = vT + ((size_t)(bb * 64 + dbase)) * 1024 + n;
    vt[0]        = o[0];
    vt[1024]     = o[1];
    vt[2048]     = o[2];
    vt[3072]     = o[3];
  }
}

// ------------------------------- Attention ---------------------------------
// MQA flash attention. QBLK=32/wave; 4 waves/block; heads h=hg*4+wave.
// K tiles from kv[b][n][0..63]; V^T tiles from vT[b][d][n] — both staged via
// global_load_lds into double-buffered, XOR-swizzled LDS (ff1 pattern:
// source chunk (l&7)^(l>>3); ds_read chunk (kh*4+lgrp)^(row&7)).
// Counted vmcnt(4): next tile's 4 loads stay in flight through compute.
__global__ __launch_bounds__(256) void attn_kernel(const short* __restrict__ q,
                                                   const short* __restrict__ kv,
                                                   const short* __restrict__ vT,
                                                   short* __restrict__ ao)
{
  __shared__ __align__(16) short Ks[2][64 * 64];   // [kv][d] swizzled, 2x8KB
  __shared__ __align__(16) short Vt[2][64 * 64];   // [d][kv] swizzled, 2x8KB
  __shared__ __align__(16) short Ps[4][32 * 64];   // per-wave [q][kv] swizzled

  int t = threadIdx.x;
  int lane = t & 63, wave = t >> 6;
  int lrow = lane & 15, lgrp = lane >> 4;
  int qt = blockIdx.x;
  int b = blockIdx.y >> 2, hg = blockIdx.y & 3;
  int h = hg * 4 + wave;

  char* Pb = (char*)Ps + wave * (32 * 64 * 2);

  // staging addresses: line = 8 rows x 128B; lane l -> row +(l>>3),
  // source chunk pre-swizzled (l&7)^(l>>3); LDS dest linear.
  int r8 = lane >> 3;
  int schunk = ((lane & 7) ^ r8) * 8;
  const short* gK = kv + ((size_t)(b * 1024 + wave * 16 + r8)) * 128 + schunk;
  const short* gV = vT + ((size_t)(b * 64 + wave * 16 + r8)) * 1024 + schunk;

  auto STAGE = [&](int buf, int j0) {
    gload16(gK + (size_t)(j0 + 0) * 128, &Ks[buf][(wave * 16 + 0) * 64]);
    gload16(gK + (size_t)(j0 + 8) * 128, &Ks[buf][(wave * 16 + 8) * 64]);
    gload16(gV + j0,                     &Vt[buf][(wave * 16 + 0) * 64]);
    gload16(gV + (size_t)8 * 1024 + j0,  &Vt[buf][(wave * 16 + 8) * 64]);
  };

  bf16x8 qf[2][2];
  const short* qb = q + ((size_t)(b * 1024 + qt * 32)) * 1024 + h * 64;
#pragma unroll
  for (int mf = 0; mf < 2; mf++)
#pragma unroll
    for (int kk = 0; kk < 2; kk++)
      qf[mf][kk] = *(const bf16x8*)&qb[(size_t)(mf * 16 + lrow) * 1024 + kk * 32 + lgrp * 8];

  f32x4 oacc[2][4];
  float m_[2][4], l_[2][4];
  const f32x4 zero = { 0.f, 0.f, 0.f, 0.f };
#pragma unroll
  for (int i = 0; i < 2; i++)
#pragma unroll
    for (int j = 0; j < 4; j++) { oacc[i][j] = zero; }
#pragma unroll
  for (int i = 0; i < 2; i++)
#pragma unroll
    for (int r = 0; r < 4; r++) { m_[i][r] = -3.0e38f; l_[i][r] = 0.f; }

  STAGE(0, 0);

  for (int tI = 0; tI < 16; ++tI) {
    int cur = tI & 1;
    int j0 = tI * 64;
    // all waves done reading buf[cur^1] (tile tI-1) before restage
    __builtin_amdgcn_s_barrier();
    __builtin_amdgcn_sched_barrier(0);
    if (tI + 1 < 16) STAGE(cur ^ 1, j0 + 64);
    __builtin_amdgcn_sched_barrier(0);
    if (tI + 1 < 16) asm volatile("s_waitcnt vmcnt(4)" ::: "memory");
    else             asm volatile("s_waitcnt vmcnt(0)" ::: "memory");
    __builtin_amdgcn_s_barrier();     // tile tI data visible to all waves
    __builtin_amdgcn_sched_barrier(0);

    // ---- S = Q @ K^T ----
    bf16x8 kf[4][2];
#pragma unroll
    for (int nf = 0; nf < 4; nf++) {
      int row = nf * 16 + lrow;
      kf[nf][0] = *(const bf16x8*)&Ks[cur][row * 64 + ((lgrp ^ (row & 7)) * 8)];
      kf[nf][1] = *(const bf16x8*)&Ks[cur][row * 64 + (((4 | lgrp) ^ (row & 7)) * 8)];
    }
    f32x4 sacc[2][4];
#pragma unroll
    for (int i = 0; i < 2; i++)
#pragma unroll
      for (int j = 0; j < 4; j++) sacc[i][j] = zero;
    __builtin_amdgcn_s_setprio(1);
#pragma unroll
    for (int mf = 0; mf < 2; mf++)
#pragma unroll
      for (int nf = 0; nf < 4; nf++)
#pragma unroll
        for (int kk = 0; kk < 2; kk++)
          sacc[mf][nf] = __builtin_amdgcn_mfma_f32_16x16x32_bf16(qf[mf][kk], kf[nf][kk], sacc[mf][nf], 0, 0, 0);
    __builtin_amdgcn_s_setprio(0);

    // ---- online softmax with defer-max (T13) ----
    float pmax[2][4];
    bool okd = true;
#pragma unroll
    for (int mf = 0; mf < 2; mf++)
#pragma unroll
      for (int r = 0; r < 4; r++) {
        float pm = fmaxf(fmaxf(sacc[mf][0][r], sacc[mf][1][r]),
                         fmaxf(sacc[mf][2][r], sacc[mf][3][r]));
        pmax[mf][r] = pm;
        okd = okd && (pm <= m_[mf][r] + 8.0f);
      }
    if (__all(okd)) {
#pragma unroll
      for (int mf = 0; mf < 2; mf++)
#pragma unroll
        for (int r = 0; r < 4; r++) {
          int row = mf * 16 + lgrp * 4 + r, sw = (row & 7) << 4;
          float al = 0.f;
#pragma unroll
          for (int nf = 0; nf < 4; nf++) {
            float p = __expf(sacc[mf][nf][r] - m_[mf][r]);
            *(short*)(Pb + row * 128 + (((nf * 16 + lrow) * 2) ^ sw)) = f2b(p);
            al += p;
          }
          l_[mf][r] += al;
        }
    } else {
#pragma unroll
      for (int mf = 0; mf < 2; mf++)
#pragma unroll
        for (int r = 0; r < 4; r++) {
          float mx = pmax[mf][r];
#pragma unroll
          for (int o = 8; o >= 1; o >>= 1) mx = fmaxf(mx, __shfl_xor(mx, o));
          float mnew = fmaxf(m_[mf][r], mx);
          float corr = __expf(m_[mf][r] - mnew);
          int row = mf * 16 + lgrp * 4 + r, sw = (row & 7) << 4;
          float al = 0.f;
#pragma unroll
          for (int nf = 0; nf < 4; nf++) {
            float p = __expf(sacc[mf][nf][r] - mnew);
            *(short*)(Pb + row * 128 + (((nf * 16 + lrow) * 2) ^ sw)) = f2b(p);
            al += p;
          }
          l_[mf][r] = l_[mf][r] * corr + al;
          m_[mf][r] = mnew;
#pragma unroll
          for (int nf = 0; nf < 4; nf++) oacc[mf][nf][r] *= corr;
        }
    }

    // ---- O += P @ V ----  (V^T in LDS: B row = d; P wave-private)
    bf16x8 vf[4][2], pfr[2][2];
#pragma unroll
    for (int nf = 0; nf < 4; nf++) {
      int row = nf * 16 + lrow;
      vf[nf][0] = *(const bf16x8*)&Vt[cur][row * 64 + ((lgrp ^ (row & 7)) * 8)];
      vf[nf][1] = *(const bf16x8*)&Vt[cur][row * 64 + (((4 | lgrp) ^ (row & 7)) * 8)];
    }
#pragma unroll
    for (int mf = 0; mf < 2; mf++) {
      int row = mf * 16 + lrow, sw = (row & 7) << 4;
      pfr[mf][0] = *(const bf16x8*)(Pb + row * 128 + ((lgrp * 16) ^ sw));
      pfr[mf][1] = *(const bf16x8*)(Pb + row * 128 + ((64 + lgrp * 16) ^ sw));
    }
    __builtin_amdgcn_s_setprio(1);
#pragma unroll
    for (int mf = 0; mf < 2; mf++)
#pragma unroll
      for (int nf = 0; nf < 4; nf++)
#pragma unroll
        for (int kk = 0; kk < 2; kk++)
          oacc[mf][nf] = __builtin_amdgcn_mfma_f32_16x16x32_bf16(pfr[mf][kk], vf[nf][kk], oacc[mf][nf], 0, 0, 0);
    __builtin_amdgcn_s_setprio(0);
  }

  // final l reduction + write
#pragma unroll
  for (int mf = 0; mf < 2; mf++)
#pragma unroll
    for (int r = 0; r < 4; r++) {
      float ls = l_[mf][r];
#pragma unroll
      for (int o = 8; o >= 1; o >>= 1) ls += __shfl_xor(ls, o);
      float inv = 1.0f / ls;
      int qrow = qt * 32 + mf * 16 + lgrp * 4 + r;
#pragma unroll
      for (int nf = 0; nf < 4; nf++) {
        float val = oacc[mf][nf][r] * inv;
        ao[((size_t)(b * 1024 + qrow)) * 1024 + h * 64 + nf * 16 + lrow] = f2b(val);
      }
    }
}

// ------------------------------- launcher ----------------------------------
extern "C" void kernel_launch(void* const* d_in, const int* in_sizes, int n_in,
                              void* d_out, int out_size, void* d_ws, size_t ws_size,
                              hipStream_t stream) {
  const float* x     = (const float*)d_in[0];
  const float* y     = (const float*)d_in[1];
  const float* g1    = (const float*)d_in[2];
  const float* g2    = (const float*)d_in[3];
  const float* g_out = (const float*)d_in[4];
  const float* Wq    = (const float*)d_in[5];
  const float* Wkv   = (const float*)d_in[6];
  const float* Wo    = (const float*)d_in[7];
  const float* Wff1  = (const float*)d_in[8];
  const float* Wff2  = (const float*)d_in[9];

  char* ws = (char*)d_ws;
  size_t off = 0;
  auto alloc = [&](size_t bytes) { char* p = ws + off; off += bytes; return p; };
  short* wqT    = (short*)alloc((size_t)1024 * 1024 * 2);   // [1024][1024]
  short* wkvT   = (short*)alloc((size_t)128 * 1024 * 2);    // [128][1024]
  short* woT    = (short*)alloc((size_t)1024 * 1024 * 2);   // [1024][1024]
  short* wff1T  = (short*)alloc((size_t)8192 * 1024 * 2);   // [8192][1024]
  short* wff2T  = (short*)alloc((size_t)1024 * 4096 * 2);   // [1024][4096]
  short* xn16   = (short*)alloc((size_t)4096 * 1024 * 2);
  short* yn16   = (short*)alloc((size_t)4096 * 1024 * 2);
  float* ynf    = (float*)alloc((size_t)4096 * 1024 * 4);
  short* q16    = (short*)alloc((size_t)4096 * 1024 * 2);
  short* kv16   = (short*)alloc((size_t)4096 * 128 * 2);
  short* vT16   = (short*)alloc((size_t)4 * 64 * 1024 * 2);
  short* ao16   = (short*)alloc((size_t)4096 * 1024 * 2);
  float* lnout  = (float*)alloc((size_t)4096 * 1024 * 4);
  short* act16  = (short*)alloc((size_t)4096 * 4096 * 2);
  float* kvpart = (float*)alloc((size_t)4 * 4096 * 128 * 4);
  float* outf   = (float*)d_out;

  // weight transpose-convert: [K][N] f32 -> [N][K] bf16
  cvtT_kernel<<<dim3(1024 / 32, 1024 / 32), 256, 0, stream>>>(Wq,   wqT,   1024, 1024);
  cvtT_kernel<<<dim3(128 / 32, 1024 / 32),  256, 0, stream>>>(Wkv,  wkvT,  1024, 128);
  cvtT_kernel<<<dim3(1024 / 32, 1024 / 32), 256, 0, stream>>>(Wo,   woT,   1024, 1024);
  cvtT_kernel<<<dim3(8192 / 32, 1024 / 32), 256, 0, stream>>>(Wff1, wff1T, 1024, 8192);
  cvtT_kernel<<<dim3(1024 / 32, 4096 / 32), 256, 0, stream>>>(Wff2, wff2T, 4096, 1024);

  // LayerNorms
  ln_kernel<<<4096, 256, 0, stream>>>(x, g1, xn16, nullptr);
  ln_kernel<<<4096, 256, 0, stream>>>(y, g2, yn16, ynf);

  // q = (xn @ Wq) * 1/8   [BM=64: 512 blocks]
  gemm_ring<0, 64, 128><<<dim3(8, 64), 256, 0, stream>>>(
      xn16, wqT, 4096, 1024, 1024, 1024, q16, nullptr, nullptr, 0.125f);
  // kv = yn @ Wkv   [split-K x4; f32 partials] -> kv16 + vT16
  gemm_ring<3, 64, 128><<<dim3(1, 64, 4), 256, 0, stream>>>(
      yn16, wkvT, 4096, 128, 1024, 256, nullptr, kvpart, nullptr, 1.0f);
  kvred_kernel<<<512, 256, 0, stream>>>(kvpart, kv16, vT16);

  // attention
  attn_kernel<<<dim3(32, 16), 256, 0, stream>>>(q16, kv16, vT16, ao16);

  // out = attn @ Wo + yn   (f32, into d_out as scratch)
  gemm_ring<1, 64, 128><<<dim3(8, 64), 256, 0, stream>>>(
      ao16, woT, 4096, 1024, 1024, 1024, nullptr, outf, ynf, 1.0f);

  // ln_out = LN(out) * g_out  (f32)
  ln_kernel<<<4096, 256, 0, stream>>>(outf, g_out, nullptr, lnout);

  // act = silu(gate) * val   (m201-style 8-phase fused SwiGLU GEMM)
  gemm_ff1<<<dim3(32, 16), 512, 0, stream>>>(yn16, wff1T, act16);

  // d_out = act @ Wff2 + ln_out
  gemm_ring<1, 64, 128><<<dim3(8, 64), 256, 0, stream>>>(
      act16, wff2T, 4096, 1024, 4096, 4096, nullptr, outf, lnout, 1.0f);
}